// Round 6
// baseline (533.893 us; speedup 1.0000x reference)
//
#include <hip/hip_runtime.h>
#include <hip/hip_bf16.h>

#define IN_DIM 768
#define HID 256
#define OUT_DIM 128
#define NHEAD 8
#define NREL 6
#define RD 64

typedef unsigned short ushort_t;
typedef float f32x4 __attribute__((ext_vector_type(4)));
typedef __bf16 bf16x8 __attribute__((ext_vector_type(8)));
typedef unsigned short u16x8 __attribute__((ext_vector_type(8)));
typedef unsigned short u16x4 __attribute__((ext_vector_type(4)));
typedef unsigned short u16x2 __attribute__((ext_vector_type(2)));

static __device__ __forceinline__ float leaky(float x) { return x > 0.f ? x : 0.2f * x; }

static __device__ __forceinline__ ushort_t f2bf(float f) {
    union { __hip_bfloat16 h; ushort_t u; } c;
    c.h = __float2bfloat16(f);
    return c.u;
}

static __device__ __forceinline__ float b2f(ushort_t u) {
    union { unsigned int i; float f; } c;
    c.i = ((unsigned int)u) << 16;
    return c.f;
}

// ---------------- CSR build ----------------
__global__ void count_kernel(const int* __restrict__ dst0, const int* __restrict__ ety,
                             int* __restrict__ deg, int* __restrict__ relcnt, int E) {
    int e = blockIdx.x * blockDim.x + threadIdx.x;
    if (e >= E) return;
    int d = dst0[e];
    atomicAdd(&deg[d], 1);
    atomicAdd(&relcnt[d * NREL + ety[e]], 1);
}

// one-pass scan: per-thread serial sum -> wave shfl scan -> t0 combines 16 wave sums
__global__ void __launch_bounds__(1024) scan_kernel(const int* __restrict__ deg,
                                                    int* __restrict__ rowptr, int n) {
    __shared__ int wsum[16];
    __shared__ int wbase[16];
    int t = threadIdx.x;
    int per = (n + 1023) >> 10;
    int start = t * per;
    int end = min(start + per, n);
    int s = 0;
    for (int i = start; i < end; i++) s += deg[i];
    int lane = t & 63, w = t >> 6;
    int v = s;
    for (int o = 1; o < 64; o <<= 1) {
        int u = __shfl_up(v, o, 64);
        if (lane >= o) v += u;
    }
    if (lane == 63) wsum[w] = v;
    __syncthreads();
    if (t == 0) {
        int run = 0;
        for (int i = 0; i < 16; i++) {
            wbase[i] = run;
            run += wsum[i];
        }
        rowptr[n] = run;
    }
    __syncthreads();
    int run = wbase[w] + (v - s);
    for (int i = start; i < end; i++) {
        rowptr[i] = run;
        run += deg[i];
    }
}

// packs src | (type<<24) into one word (one scattered stream instead of two)
__global__ void scatter_kernel(const int* __restrict__ src0, const int* __restrict__ dst0,
                               const int* __restrict__ ety, const int* __restrict__ rowptr,
                               int* __restrict__ fill, int* __restrict__ src_pk, int E) {
    int e = blockIdx.x * blockDim.x + threadIdx.x;
    if (e >= E) return;
    int d = dst0[e];
    int pos = rowptr[d] + atomicAdd(&fill[d], 1);
    src_pk[pos] = src0[e] | (ety[e] << 24);
}

// rel_alpha[r][h] = sum_c (rel_emb[r] @ We1)[h*32+c] * att_e1[h][c]
__global__ void rel_alpha_kernel(const float* __restrict__ rel_emb, const float* __restrict__ We1,
                                 const float* __restrict__ att_e1, float* __restrict__ rel_alpha) {
    int t = threadIdx.x;
    if (t >= NREL * NHEAD) return;
    int r = t / NHEAD, h = t % NHEAD;
    float acc = 0.f;
    for (int c = 0; c < HID / NHEAD; c++) {
        float v = 0.f;
        for (int k = 0; k < RD; k++) v += rel_emb[r * RD + k] * We1[k * HID + h * 32 + c];
        acc += v * att_e1[h * 32 + c];
    }
    rel_alpha[r * NHEAD + h] = acc;
}

// W[K][Nc] fp32 -> Wt[Nc][K] bf16
__global__ void transpose_conv(const float* __restrict__ W, ushort_t* __restrict__ Wt,
                               int K, int Nc) {
    int i = blockIdx.x * 256 + threadIdx.x;
    if (i >= K * Nc) return;
    int k = i / Nc, n = i % Nc;
    Wt[n * K + k] = f2bf(W[i]);
}

// ---------------- MFMA bf16 GEMM: C[M,Nout](bf16) = A[M,K] @ Bt[Nout,K]^T ----------------
// 128x128 tile, BK=64, 4 waves, reg-prefetch 2-phase pipeline.
// COALESCED staging: AF32 thread t <-> (row t/16 + 16i, fp32 cols (t%16)*4): lanes 0-15
// read 256 B contiguous -> ~16 cache lines/instr (was 64 with row=t/2 mapping).
// bf16/B: thread t <-> (row t/8 + 32i, cols (t%8)*8), 16 lines/instr.
template <bool AF32>
__global__ void __launch_bounds__(256) gemm_mfma(const float* __restrict__ Af,
                                                 const ushort_t* __restrict__ Ab,
                                                 const ushort_t* __restrict__ Bt,
                                                 ushort_t* __restrict__ C,
                                                 int M, int K, int Nout, int NBlk) {
    __shared__ ushort_t sA[128 * 72];
    __shared__ ushort_t sB[128 * 72];
    int T = gridDim.x;
    int p = blockIdx.x;
    int q = T >> 3, rr8 = T & 7, xc = p & 7, j = p >> 3;
    int l = (xc < rr8 ? xc * (q + 1) : rr8 * (q + 1) + (xc - rr8) * q) + j;
    int m0 = (l / NBlk) * 128;
    int n0 = (l % NBlk) * 128;
    int t = threadIdx.x;
    int w = t >> 6, ln = t & 63;
    int wm = (w >> 1) * 64, wn = (w & 1) * 64;

    int arow = t >> 4;          // AF32 base row (0..15), step 16
    int acol = (t & 15) << 2;   // fp32 col group
    int brow = t >> 3;          // bf16 base row (0..31), step 32
    int bcol = (t & 7) << 3;    // bf16 col group

    float4 fa[8];
    u16x8 rab[4];
    u16x8 rb[4];
    f32x4 acc[4][4] = {};

    const float* aF = Af + (size_t)m0 * K;
    const ushort_t* aB = Ab + (size_t)m0 * K;
    const ushort_t* bB = Bt + (size_t)n0 * K;

    auto load_tile = [&](int k0) {
        if (AF32) {
#pragma unroll
            for (int i = 0; i < 8; i++) {
                int row = arow + 16 * i;
                if (m0 + row < M)
                    fa[i] = *reinterpret_cast<const float4*>(aF + (size_t)row * K + k0 + acol);
                else
                    fa[i] = make_float4(0.f, 0.f, 0.f, 0.f);
            }
        } else {
#pragma unroll
            for (int i = 0; i < 4; i++) {
                int row = brow + 32 * i;
                rab[i] = *reinterpret_cast<const u16x8*>(aB + (size_t)row * K + k0 + bcol);
            }
        }
#pragma unroll
        for (int i = 0; i < 4; i++) {
            int row = brow + 32 * i;
            rb[i] = *reinterpret_cast<const u16x8*>(bB + (size_t)row * K + k0 + bcol);
        }
    };

    auto store_lds = [&]() {
        if (AF32) {
#pragma unroll
            for (int i = 0; i < 8; i++) {
                u16x4 o;
                o[0] = f2bf(fa[i].x);
                o[1] = f2bf(fa[i].y);
                o[2] = f2bf(fa[i].z);
                o[3] = f2bf(fa[i].w);
                *reinterpret_cast<u16x4*>(&sA[(arow + 16 * i) * 72 + acol]) = o;
            }
        } else {
#pragma unroll
            for (int i = 0; i < 4; i++)
                *reinterpret_cast<u16x8*>(&sA[(brow + 32 * i) * 72 + bcol]) = rab[i];
        }
#pragma unroll
        for (int i = 0; i < 4; i++)
            *reinterpret_cast<u16x8*>(&sB[(brow + 32 * i) * 72 + bcol]) = rb[i];
    };

    auto compute = [&]() {
#pragma unroll
        for (int ks = 0; ks < 2; ks++) {
            bf16x8 af[4], bfr[4];
#pragma unroll
            for (int m = 0; m < 4; m++)
                af[m] = *reinterpret_cast<const bf16x8*>(
                    &sA[(wm + m * 16 + (ln & 15)) * 72 + ks * 32 + (ln >> 4) * 8]);
#pragma unroll
            for (int n = 0; n < 4; n++)
                bfr[n] = *reinterpret_cast<const bf16x8*>(
                    &sB[(wn + n * 16 + (ln & 15)) * 72 + ks * 32 + (ln >> 4) * 8]);
#pragma unroll
            for (int m = 0; m < 4; m++)
#pragma unroll
                for (int n = 0; n < 4; n++)
                    acc[m][n] = __builtin_amdgcn_mfma_f32_16x16x32_bf16(af[m], bfr[n], acc[m][n], 0, 0, 0);
        }
    };

    load_tile(0);
    store_lds();
    __syncthreads();
    for (int k0 = 64; k0 < K; k0 += 64) {
        load_tile(k0);   // next tile -> regs (hides under compute)
        compute();       // consume current LDS tile
        __syncthreads();
        store_lds();
        __syncthreads();
    }
    compute();

#pragma unroll
    for (int m = 0; m < 4; m++) {
#pragma unroll
        for (int rr = 0; rr < 4; rr++) {
            int row = m0 + wm + m * 16 + (ln >> 4) * 4 + rr;
#pragma unroll
            for (int n = 0; n < 4; n++)
                C[(size_t)row * Nout + n0 + wn + n * 16 + (ln & 15)] = f2bf(acc[m][n][rr]);
        }
    }
}

// ---------------- per-node attention scalars, layer 1 (bf16 h1) ----------------
__global__ void __launch_bounds__(256) alpha1_kernel(const ushort_t* __restrict__ h1b,
                                                     const float* __restrict__ att_s,
                                                     const float* __restrict__ att_d,
                                                     const int* __restrict__ relcnt,
                                                     const int* __restrict__ deg,
                                                     const float* __restrict__ rel_alpha,
                                                     float* __restrict__ als, float* __restrict__ ald,
                                                     float* __restrict__ selfa) {
    int i = blockIdx.x, t = threadIdx.x;
    int h = t >> 5, l = t & 31;
    float v = b2f(h1b[(size_t)i * HID + t]);
    float ps = v * att_s[t], pd = v * att_d[t];
    for (int o = 16; o > 0; o >>= 1) {
        ps += __shfl_xor(ps, o, 32);
        pd += __shfl_xor(pd, o, 32);
    }
    if (l == 0) {
        als[i * NHEAD + h] = ps;
        ald[i * NHEAD + h] = pd;
    }
    if (t < NHEAD) {
        float dv = fmaxf((float)deg[i], 1.0f);
        float acc = 0.f;
        for (int r = 0; r < NREL; r++) acc += (float)relcnt[i * NREL + r] * rel_alpha[r * NHEAD + t];
        selfa[i * NHEAD + t] = acc / dv;
    }
}

// ---------------- fused layer-1 aggregation: ONE WAVE PER NODE, zero barriers ----------------
__global__ void __launch_bounds__(256) node_agg1(
    const ushort_t* __restrict__ h1b, const float* __restrict__ als, const float* __restrict__ ald,
    const float* __restrict__ selfa, const float* __restrict__ rel_alpha,
    const int* __restrict__ rowptr, const int* __restrict__ src_pk,
    const float* __restrict__ b1, const float* __restrict__ g1, const float* __restrict__ beta1,
    ushort_t* __restrict__ out, int N) {
    __shared__ float sh_rel[NREL * NHEAD];
    __shared__ float sh_aw[4][64 * NHEAD];   // per-wave [edge][head]
    __shared__ unsigned sh_off[4][64];       // per-wave row byte offsets
    int w = threadIdx.x >> 6, l = threadIdx.x & 63;
    if (threadIdx.x < NREL * NHEAD) sh_rel[threadIdx.x] = rel_alpha[threadIdx.x];
    __syncthreads();  // only barrier: publish sh_rel
    int i = blockIdx.x * 4 + w;
    if (i >= N) return;
    int hd = l >> 3;
    int sub = l & 7;
    float m = leaky(als[i * NHEAD + hd] + ald[i * NHEAD + hd] + selfa[i * NHEAD + hd]);
    float s = 1.0f;
    float ald_stage = ald[i * NHEAD + sub];
    float acc0, acc1, acc2, acc3;
    {
        u16x4 v = *reinterpret_cast<const u16x4*>(h1b + (size_t)i * HID + 4 * l);
        acc0 = b2f(v[0]); acc1 = b2f(v[1]); acc2 = b2f(v[2]); acc3 = b2f(v[3]);
    }
    int base = rowptr[i];
    int deg = rowptr[i + 1] - base;
    const char* hb = reinterpret_cast<const char*>(h1b);
    for (int cs = 0; cs < deg; cs += 64) {
        int c = min(64, deg - cs);
        for (int p = 0; p * 8 < c; p++) {
            int e = p * 8 + (l >> 3);
            if (e < c) {
                int pk = src_pk[base + cs + e];
                int sv = pk & 0xFFFFFF;
                int tv = (unsigned)pk >> 24;
                float a = als[sv * NHEAD + sub] + ald_stage + sh_rel[tv * NHEAD + sub];
                sh_aw[w][e * NHEAD + sub] = leaky(a);
                if (sub == 0) sh_off[w][e] = (unsigned)sv * (HID * 2);
            }
        }
        float cm = -1e30f;
        for (int e = sub; e < c; e += 8) cm = fmaxf(cm, sh_aw[w][e * NHEAD + hd]);
        for (int o = 1; o < 8; o <<= 1) cm = fmaxf(cm, __shfl_xor(cm, o, 64));
        float nm = fmaxf(m, cm);
        float f = __expf(m - nm);
        float csum = 0.f;
        for (int e = sub; e < c; e += 8) {
            float ww = __expf(sh_aw[w][e * NHEAD + hd] - nm);
            sh_aw[w][e * NHEAD + hd] = ww;
            csum += ww;
        }
        for (int o = 1; o < 8; o <<= 1) csum += __shfl_xor(csum, o, 64);
        s = s * f + csum;
        m = nm;
        acc0 *= f; acc1 *= f; acc2 *= f; acc3 *= f;
        int e = 0;
        for (; e + 4 <= c; e += 4) {
            unsigned o0 = sh_off[w][e], o1 = sh_off[w][e + 1];
            unsigned o2 = sh_off[w][e + 2], o3 = sh_off[w][e + 3];
            float w0 = sh_aw[w][e * NHEAD + hd], w1 = sh_aw[w][(e + 1) * NHEAD + hd];
            float w2 = sh_aw[w][(e + 2) * NHEAD + hd], w3 = sh_aw[w][(e + 3) * NHEAD + hd];
            u16x4 v0 = *reinterpret_cast<const u16x4*>(hb + o0 + 8 * l);
            u16x4 v1 = *reinterpret_cast<const u16x4*>(hb + o1 + 8 * l);
            u16x4 v2 = *reinterpret_cast<const u16x4*>(hb + o2 + 8 * l);
            u16x4 v3 = *reinterpret_cast<const u16x4*>(hb + o3 + 8 * l);
            acc0 += w0 * b2f(v0[0]) + w1 * b2f(v1[0]) + w2 * b2f(v2[0]) + w3 * b2f(v3[0]);
            acc1 += w0 * b2f(v0[1]) + w1 * b2f(v1[1]) + w2 * b2f(v2[1]) + w3 * b2f(v3[1]);
            acc2 += w0 * b2f(v0[2]) + w1 * b2f(v1[2]) + w2 * b2f(v2[2]) + w3 * b2f(v3[2]);
            acc3 += w0 * b2f(v0[3]) + w1 * b2f(v1[3]) + w2 * b2f(v2[3]) + w3 * b2f(v3[3]);
        }
        for (; e < c; e++) {
            unsigned o0 = sh_off[w][e];
            float w0 = sh_aw[w][e * NHEAD + hd];
            u16x4 v0 = *reinterpret_cast<const u16x4*>(hb + o0 + 8 * l);
            acc0 += w0 * b2f(v0[0]); acc1 += w0 * b2f(v0[1]);
            acc2 += w0 * b2f(v0[2]); acc3 += w0 * b2f(v0[3]);
        }
    }
    float inv = 1.0f / (s + 1e-16f);
    float4 bb = *reinterpret_cast<const float4*>(b1 + 4 * l);
    float y0 = acc0 * inv + bb.x, y1 = acc1 * inv + bb.y;
    float y2 = acc2 * inv + bb.z, y3 = acc3 * inv + bb.w;
    float su = y0 + y1 + y2 + y3;
    float sq = y0 * y0 + y1 * y1 + y2 * y2 + y3 * y3;
    for (int o = 1; o < 64; o <<= 1) {
        su += __shfl_xor(su, o, 64);
        sq += __shfl_xor(sq, o, 64);
    }
    float mean = su * (1.f / 256.f);
    float var = sq * (1.f / 256.f) - mean * mean;
    float rstd = rsqrtf(var + 1e-5f);
    float4 gg = *reinterpret_cast<const float4*>(g1 + 4 * l);
    float4 be = *reinterpret_cast<const float4*>(beta1 + 4 * l);
    float z0 = (y0 - mean) * rstd * gg.x + be.x;
    float z1 = (y1 - mean) * rstd * gg.y + be.y;
    float z2 = (y2 - mean) * rstd * gg.z + be.z;
    float z3 = (y3 - mean) * rstd * gg.w + be.w;
    u16x4 ov;
    ov[0] = f2bf(z0 > 0.f ? z0 : __expf(z0) - 1.f);
    ov[1] = f2bf(z1 > 0.f ? z1 : __expf(z1) - 1.f);
    ov[2] = f2bf(z2 > 0.f ? z2 : __expf(z2) - 1.f);
    ov[3] = f2bf(z3 > 0.f ? z3 : __expf(z3) - 1.f);
    *reinterpret_cast<u16x4*>(out + (size_t)i * HID + 4 * l) = ov;
}

// ---------------- per-node attention scalars, layer 2 (1 head, bf16 h2) ----------------
__global__ void __launch_bounds__(128) alpha2_kernel(const ushort_t* __restrict__ h2b,
                                                     const float* __restrict__ att_s,
                                                     const float* __restrict__ att_d,
                                                     float* __restrict__ als, float* __restrict__ ald) {
    int i = blockIdx.x, t = threadIdx.x;
    float v = b2f(h2b[(size_t)i * OUT_DIM + t]);
    float ps = v * att_s[t], pd = v * att_d[t];
    for (int o = 32; o > 0; o >>= 1) {
        ps += __shfl_xor(ps, o, 64);
        pd += __shfl_xor(pd, o, 64);
    }
    __shared__ float r0[2], r1[2];
    if ((t & 63) == 0) {
        r0[t >> 6] = ps;
        r1[t >> 6] = pd;
    }
    __syncthreads();
    if (t == 0) {
        als[i] = r0[0] + r0[1];
        ald[i] = r1[0] + r1[1];
    }
}

// ---------------- fused layer-2 aggregation: ONE WAVE PER NODE ----------------
__global__ void __launch_bounds__(256) node_agg2(const ushort_t* __restrict__ h2b,
                                                 const float* __restrict__ als,
                                                 const float* __restrict__ ald,
                                                 const int* __restrict__ rowptr,
                                                 const int* __restrict__ src_pk,
                                                 const float* __restrict__ b2,
                                                 const float* __restrict__ g2,
                                                 const float* __restrict__ beta2,
                                                 float* __restrict__ out, int N) {
    __shared__ float sh_a[4][64];
    __shared__ unsigned sh_off[4][64];
    int w = threadIdx.x >> 6, l = threadIdx.x & 63;
    int i = blockIdx.x * 4 + w;
    if (i >= N) return;
    float aldi = ald[i];
    float m = leaky(als[i] + aldi);
    float s = 1.0f;
    float acc0, acc1;
    {
        u16x2 v = *reinterpret_cast<const u16x2*>(h2b + (size_t)i * OUT_DIM + 2 * l);
        acc0 = b2f(v[0]); acc1 = b2f(v[1]);
    }
    int base = rowptr[i];
    int deg = rowptr[i + 1] - base;
    const char* hb = reinterpret_cast<const char*>(h2b);
    for (int cs = 0; cs < deg; cs += 64) {
        int c = min(64, deg - cs);
        float a = -1e30f;
        if (l < c) {
            int sv = src_pk[base + cs + l] & 0xFFFFFF;
            a = leaky(als[sv] + aldi);
            sh_off[w][l] = (unsigned)sv * (OUT_DIM * 2);
        }
        float cm = a;
        for (int o = 1; o < 64; o <<= 1) cm = fmaxf(cm, __shfl_xor(cm, o, 64));
        float nm = fmaxf(m, cm);
        float f = __expf(m - nm);
        float ww = (l < c) ? __expf(a - nm) : 0.f;
        sh_a[w][l] = ww;
        float csum = ww;
        for (int o = 1; o < 64; o <<= 1) csum += __shfl_xor(csum, o, 64);
        s = s * f + csum;
        m = nm;
        acc0 *= f; acc1 *= f;
        int e = 0;
        for (; e + 4 <= c; e += 4) {
            unsigned o0 = sh_off[w][e], o1 = sh_off[w][e + 1];
            unsigned o2 = sh_off[w][e + 2], o3 = sh_off[w][e + 3];
            float w0 = sh_a[w][e], w1 = sh_a[w][e + 1];
            float w2 = sh_a[w][e + 2], w3 = sh_a[w][e + 3];
            u16x2 v0 = *reinterpret_cast<const u16x2*>(hb + o0 + 4 * l);
            u16x2 v1 = *reinterpret_cast<const u16x2*>(hb + o1 + 4 * l);
            u16x2 v2 = *reinterpret_cast<const u16x2*>(hb + o2 + 4 * l);
            u16x2 v3 = *reinterpret_cast<const u16x2*>(hb + o3 + 4 * l);
            acc0 += w0 * b2f(v0[0]) + w1 * b2f(v1[0]) + w2 * b2f(v2[0]) + w3 * b2f(v3[0]);
            acc1 += w0 * b2f(v0[1]) + w1 * b2f(v1[1]) + w2 * b2f(v2[1]) + w3 * b2f(v3[1]);
        }
        for (; e < c; e++) {
            unsigned o0 = sh_off[w][e];
            float w0 = sh_a[w][e];
            u16x2 v0 = *reinterpret_cast<const u16x2*>(hb + o0 + 4 * l);
            acc0 += w0 * b2f(v0[0]); acc1 += w0 * b2f(v0[1]);
        }
    }
    float inv = 1.0f / (s + 1e-16f);
    float2 bb = *reinterpret_cast<const float2*>(b2 + 2 * l);
    float y0 = acc0 * inv + bb.x, y1 = acc1 * inv + bb.y;
    float su = y0 + y1, sq = y0 * y0 + y1 * y1;
    for (int o = 1; o < 64; o <<= 1) {
        su += __shfl_xor(su, o, 64);
        sq += __shfl_xor(sq, o, 64);
    }
    float mean = su * (1.f / 128.f);
    float var = sq * (1.f / 128.f) - mean * mean;
    float rstd = rsqrtf(var + 1e-5f);
    float2 gg = *reinterpret_cast<const float2*>(g2 + 2 * l);
    float2 be = *reinterpret_cast<const float2*>(beta2 + 2 * l);
    float2 ov;
    ov.x = (y0 - mean) * rstd * gg.x + be.x;
    ov.y = (y1 - mean) * rstd * gg.y + be.y;
    *reinterpret_cast<float2*>(out + (size_t)i * OUT_DIM + 2 * l) = ov;
}

extern "C" void kernel_launch(void* const* d_in, const int* in_sizes, int n_in,
                              void* d_out, int out_size, void* d_ws, size_t ws_size,
                              hipStream_t stream) {
    const float* x = (const float*)d_in[0];
    const int* ei = (const int*)d_in[1];
    const int* ety = (const int*)d_in[2];
    const float* rel_emb = (const float*)d_in[3];
    const float* W1 = (const float*)d_in[4];
    const float* att_s1 = (const float*)d_in[5];
    const float* att_d1 = (const float*)d_in[6];
    const float* We1 = (const float*)d_in[7];
    const float* att_e1 = (const float*)d_in[8];
    const float* b1 = (const float*)d_in[9];
    const float* g1 = (const float*)d_in[10];
    const float* beta1 = (const float*)d_in[11];
    const float* W2 = (const float*)d_in[12];
    const float* att_s2 = (const float*)d_in[13];
    const float* att_d2 = (const float*)d_in[14];
    const float* b2 = (const float*)d_in[15];
    const float* g2 = (const float*)d_in[16];
    const float* beta2 = (const float*)d_in[17];

    int N = in_sizes[0] / IN_DIM;
    int E = in_sizes[1] / 2;
    int Mpad = ((N + 127) / 128) * 128;
    const int* src0 = ei;
    const int* dst0 = ei + E;

    char* ws = (char*)d_ws;
    size_t off = 0;
    auto alloc = [&](size_t bytes) -> void* {
        off = (off + 255) & ~(size_t)255;
        void* p = ws + off;
        off += bytes;
        return p;
    };
    int* deg = (int*)alloc((size_t)N * 4);
    int* relcnt = (int*)alloc((size_t)N * NREL * 4);
    int* fill = (int*)alloc((size_t)N * 4);
    int* rowptr = (int*)alloc((size_t)(N + 1) * 4);
    int* src_pk = (int*)alloc((size_t)E * 4);
    float* rel_alpha = (float*)alloc(NREL * NHEAD * 4);
    float* als1 = (float*)alloc((size_t)N * NHEAD * 4);
    float* ald1 = (float*)alloc((size_t)N * NHEAD * 4);
    float* selfa = (float*)alloc((size_t)N * NHEAD * 4);
    float* al2s = (float*)alloc((size_t)N * 4);
    float* al2d = (float*)alloc((size_t)N * 4);
    ushort_t* W1t = (ushort_t*)alloc((size_t)HID * IN_DIM * 2);
    ushort_t* W2t = (ushort_t*)alloc((size_t)OUT_DIM * HID * 2);
    ushort_t* h1b = (ushort_t*)alloc((size_t)Mpad * HID * 2);
    ushort_t* h1pb = (ushort_t*)alloc((size_t)Mpad * HID * 2);
    ushort_t* h2b = h1b;  // h1b dead after node_agg1 -> reuse for layer-2 features

    hipMemsetAsync(deg, 0, (size_t)N * 4, stream);
    hipMemsetAsync(relcnt, 0, (size_t)N * NREL * 4, stream);
    hipMemsetAsync(fill, 0, (size_t)N * 4, stream);
    // pad tail of h1pb: gemm2's A-staging reads rows [N, Mpad)
    hipMemsetAsync(h1pb + (size_t)N * HID, 0, (size_t)(Mpad - N) * HID * 2, stream);

    int eb = (E + 255) / 256;
    count_kernel<<<eb, 256, 0, stream>>>(dst0, ety, deg, relcnt, E);
    scan_kernel<<<1, 1024, 0, stream>>>(deg, rowptr, N);
    scatter_kernel<<<eb, 256, 0, stream>>>(src0, dst0, ety, rowptr, fill, src_pk, E);
    rel_alpha_kernel<<<1, 64, 0, stream>>>(rel_emb, We1, att_e1, rel_alpha);
    transpose_conv<<<(IN_DIM * HID + 255) / 256, 256, 0, stream>>>(W1, W1t, IN_DIM, HID);
    transpose_conv<<<(HID * OUT_DIM + 255) / 256, 256, 0, stream>>>(W2, W2t, HID, OUT_DIM);

    int NB1 = HID / 128;
    int T1 = (Mpad / 128) * NB1;
    gemm_mfma<true><<<T1, 256, 0, stream>>>(x, (const ushort_t*)nullptr, W1t, h1b, N, IN_DIM, HID, NB1);
    alpha1_kernel<<<N, 256, 0, stream>>>(h1b, att_s1, att_d1, relcnt, deg, rel_alpha, als1, ald1, selfa);
    node_agg1<<<(N + 3) / 4, 256, 0, stream>>>(h1b, als1, ald1, selfa, rel_alpha, rowptr, src_pk,
                                               b1, g1, beta1, h1pb, N);

    int NB2 = OUT_DIM / 128;
    int T2 = (Mpad / 128) * NB2;
    gemm_mfma<false><<<T2, 256, 0, stream>>>((const float*)nullptr, h1pb, W2t, h2b, N, HID, OUT_DIM, NB2);
    alpha2_kernel<<<N, 128, 0, stream>>>(h2b, att_s2, att_d2, al2s, al2d);
    node_agg2<<<(N + 3) / 4, 256, 0, stream>>>(h2b, al2s, al2d, rowptr, src_pk, b2, g2, beta2,
                                               (float*)d_out, N);
}

// Round 7
// 512.794 us; speedup vs baseline: 1.0411x; 1.0411x over previous
//
#include <hip/hip_runtime.h>
#include <hip/hip_bf16.h>

#define IN_DIM 768
#define HID 256
#define OUT_DIM 128
#define NHEAD 8
#define NREL 6
#define RD 64

typedef unsigned short ushort_t;
typedef float f32x4 __attribute__((ext_vector_type(4)));
typedef __bf16 bf16x8 __attribute__((ext_vector_type(8)));
typedef unsigned short u16x8 __attribute__((ext_vector_type(8)));
typedef unsigned short u16x4 __attribute__((ext_vector_type(4)));
typedef unsigned short u16x2 __attribute__((ext_vector_type(2)));

typedef const __attribute__((address_space(1))) void* gptr_t;
typedef __attribute__((address_space(3))) void* lptr_t;

static __device__ __forceinline__ float leaky(float x) { return x > 0.f ? x : 0.2f * x; }

static __device__ __forceinline__ ushort_t f2bf(float f) {
    union { __hip_bfloat16 h; ushort_t u; } c;
    c.h = __float2bfloat16(f);
    return c.u;
}

static __device__ __forceinline__ float b2f(ushort_t u) {
    union { unsigned int i; float f; } c;
    c.i = ((unsigned int)u) << 16;
    return c.f;
}

// ---------------- CSR build ----------------
__global__ void count_kernel(const int* __restrict__ dst0, const int* __restrict__ ety,
                             int* __restrict__ deg, int* __restrict__ relcnt, int E) {
    int e = blockIdx.x * blockDim.x + threadIdx.x;
    if (e >= E) return;
    int d = dst0[e];
    atomicAdd(&deg[d], 1);
    atomicAdd(&relcnt[d * NREL + ety[e]], 1);
}

// one-pass scan: per-thread serial sum -> wave shfl scan -> t0 combines 16 wave sums
__global__ void __launch_bounds__(1024) scan_kernel(const int* __restrict__ deg,
                                                    int* __restrict__ rowptr, int n) {
    __shared__ int wsum[16];
    __shared__ int wbase[16];
    int t = threadIdx.x;
    int per = (n + 1023) >> 10;
    int start = t * per;
    int end = min(start + per, n);
    int s = 0;
    for (int i = start; i < end; i++) s += deg[i];
    int lane = t & 63, w = t >> 6;
    int v = s;
    for (int o = 1; o < 64; o <<= 1) {
        int u = __shfl_up(v, o, 64);
        if (lane >= o) v += u;
    }
    if (lane == 63) wsum[w] = v;
    __syncthreads();
    if (t == 0) {
        int run = 0;
        for (int i = 0; i < 16; i++) {
            wbase[i] = run;
            run += wsum[i];
        }
        rowptr[n] = run;
    }
    __syncthreads();
    int run = wbase[w] + (v - s);
    for (int i = start; i < end; i++) {
        rowptr[i] = run;
        run += deg[i];
    }
}

// packs src | (type<<24) into one word (one scattered stream instead of two)
__global__ void scatter_kernel(const int* __restrict__ src0, const int* __restrict__ dst0,
                               const int* __restrict__ ety, const int* __restrict__ rowptr,
                               int* __restrict__ fill, int* __restrict__ src_pk, int E) {
    int e = blockIdx.x * blockDim.x + threadIdx.x;
    if (e >= E) return;
    int d = dst0[e];
    int pos = rowptr[d] + atomicAdd(&fill[d], 1);
    src_pk[pos] = src0[e] | (ety[e] << 24);
}

// rel_alpha[r][h] = sum_c (rel_emb[r] @ We1)[h*32+c] * att_e1[h][c]
__global__ void rel_alpha_kernel(const float* __restrict__ rel_emb, const float* __restrict__ We1,
                                 const float* __restrict__ att_e1, float* __restrict__ rel_alpha) {
    int t = threadIdx.x;
    if (t >= NREL * NHEAD) return;
    int r = t / NHEAD, h = t % NHEAD;
    float acc = 0.f;
    for (int c = 0; c < HID / NHEAD; c++) {
        float v = 0.f;
        for (int k = 0; k < RD; k++) v += rel_emb[r * RD + k] * We1[k * HID + h * 32 + c];
        acc += v * att_e1[h * 32 + c];
    }
    rel_alpha[r * NHEAD + h] = acc;
}

// W[K][Nc] fp32 -> Wt[Nc][K] bf16
__global__ void transpose_conv(const float* __restrict__ W, ushort_t* __restrict__ Wt,
                               int K, int Nc) {
    int i = blockIdx.x * 256 + threadIdx.x;
    if (i >= K * Nc) return;
    int k = i / Nc, n = i % Nc;
    Wt[n * K + k] = f2bf(W[i]);
}

// x fp32 -> xb bf16 (rows [N,Mpad) zeroed). BW-bound streaming, 8 elems/thread/iter.
__global__ void __launch_bounds__(256) conv_bf16(const float* __restrict__ x,
                                                 ushort_t* __restrict__ xb,
                                                 int total, int padtotal) {
    for (long long idx = (long long)(blockIdx.x * 256 + threadIdx.x) * 8; idx < padtotal;
         idx += (long long)gridDim.x * 256 * 8) {
        u16x8 o;
        if (idx < total) {
            float4 f0 = *reinterpret_cast<const float4*>(x + idx);
            float4 f1 = *reinterpret_cast<const float4*>(x + idx + 4);
            o[0] = f2bf(f0.x); o[1] = f2bf(f0.y); o[2] = f2bf(f0.z); o[3] = f2bf(f0.w);
            o[4] = f2bf(f1.x); o[5] = f2bf(f1.y); o[6] = f2bf(f1.z); o[7] = f2bf(f1.w);
        } else {
            o = u16x8{0, 0, 0, 0, 0, 0, 0, 0};
        }
        *reinterpret_cast<u16x8*>(xb + idx) = o;
    }
}

// ---------------- MFMA bf16 GEMM (m97 structure): C[Mpad,Nout](bf16) = A @ Bt^T ----------------
// A [Mpad,K] bf16 row-major (padded), Bt [Nout,K] bf16. 128x128 tile, BK=64, 4 waves.
// Staging via global_load_lds width=16 into LINEAR LDS [128][64]:
//   wave w, iter i covers rows w*32+i*8..+8; lane ln: global row += (ln>>3), col (ln&7)*8;
//   HW writes LDS at wave-uniform base + ln*16 == row*128B + (ln&7)*16B. (m104-compliant)
__global__ void __launch_bounds__(256) gemm_lds(const ushort_t* __restrict__ A,
                                                const ushort_t* __restrict__ Bt,
                                                ushort_t* __restrict__ C,
                                                int K, int Nout, int NBlk) {
    __shared__ ushort_t sA[128 * 64];
    __shared__ ushort_t sB[128 * 64];
    int T = gridDim.x;
    int p = blockIdx.x;
    int q = T >> 3, rr8 = T & 7, xc = p & 7, j = p >> 3;
    int l = (xc < rr8 ? xc * (q + 1) : rr8 * (q + 1) + (xc - rr8) * q) + j;
    int m0 = (l / NBlk) * 128;
    int n0 = (l % NBlk) * 128;
    int t = threadIdx.x;
    int w = t >> 6, ln = t & 63;
    int wm = (w >> 1) * 64, wn = (w & 1) * 64;

    const ushort_t* ag = A + (size_t)(m0 + w * 32 + (ln >> 3)) * K + (ln & 7) * 8;
    const ushort_t* bg = Bt + (size_t)(n0 + w * 32 + (ln >> 3)) * K + (ln & 7) * 8;

    f32x4 acc[4][4] = {};

    for (int k0 = 0; k0 < K; k0 += 64) {
#pragma unroll
        for (int i = 0; i < 4; i++) {
            __builtin_amdgcn_global_load_lds(
                (gptr_t)(const void*)(ag + (size_t)i * 8 * K + k0),
                (lptr_t)(void*)(&sA[(w * 32 + i * 8) * 64]), 16, 0, 0);
            __builtin_amdgcn_global_load_lds(
                (gptr_t)(const void*)(bg + (size_t)i * 8 * K + k0),
                (lptr_t)(void*)(&sB[(w * 32 + i * 8) * 64]), 16, 0, 0);
        }
        __syncthreads();  // compiler drains vmcnt before barrier
#pragma unroll
        for (int ks = 0; ks < 2; ks++) {
            bf16x8 af[4], bfr[4];
#pragma unroll
            for (int m = 0; m < 4; m++)
                af[m] = *reinterpret_cast<const bf16x8*>(
                    &sA[(wm + m * 16 + (ln & 15)) * 64 + ks * 32 + (ln >> 4) * 8]);
#pragma unroll
            for (int n = 0; n < 4; n++)
                bfr[n] = *reinterpret_cast<const bf16x8*>(
                    &sB[(wn + n * 16 + (ln & 15)) * 64 + ks * 32 + (ln >> 4) * 8]);
#pragma unroll
            for (int m = 0; m < 4; m++)
#pragma unroll
                for (int n = 0; n < 4; n++)
                    acc[m][n] = __builtin_amdgcn_mfma_f32_16x16x32_bf16(af[m], bfr[n], acc[m][n], 0, 0, 0);
        }
        __syncthreads();  // protect LDS for next k-step's stage
    }

#pragma unroll
    for (int m = 0; m < 4; m++) {
#pragma unroll
        for (int rr = 0; rr < 4; rr++) {
            int row = m0 + wm + m * 16 + (ln >> 4) * 4 + rr;
#pragma unroll
            for (int n = 0; n < 4; n++)
                C[(size_t)row * Nout + n0 + wn + n * 16 + (ln & 15)] = f2bf(acc[m][n][rr]);
        }
    }
}

// ---------------- per-node attention scalars, layer 1 (bf16 h1) ----------------
__global__ void __launch_bounds__(256) alpha1_kernel(const ushort_t* __restrict__ h1b,
                                                     const float* __restrict__ att_s,
                                                     const float* __restrict__ att_d,
                                                     const int* __restrict__ relcnt,
                                                     const int* __restrict__ deg,
                                                     const float* __restrict__ rel_alpha,
                                                     float* __restrict__ als, float* __restrict__ ald,
                                                     float* __restrict__ selfa) {
    int i = blockIdx.x, t = threadIdx.x;
    int h = t >> 5, l = t & 31;
    float v = b2f(h1b[(size_t)i * HID + t]);
    float ps = v * att_s[t], pd = v * att_d[t];
    for (int o = 16; o > 0; o >>= 1) {
        ps += __shfl_xor(ps, o, 32);
        pd += __shfl_xor(pd, o, 32);
    }
    if (l == 0) {
        als[i * NHEAD + h] = ps;
        ald[i * NHEAD + h] = pd;
    }
    if (t < NHEAD) {
        float dv = fmaxf((float)deg[i], 1.0f);
        float acc = 0.f;
        for (int r = 0; r < NREL; r++) acc += (float)relcnt[i * NREL + r] * rel_alpha[r * NHEAD + t];
        selfa[i * NHEAD + t] = acc / dv;
    }
}

// ---------------- fused layer-1 aggregation: ONE WAVE PER NODE, zero barriers ----------------
__global__ void __launch_bounds__(256) node_agg1(
    const ushort_t* __restrict__ h1b, const float* __restrict__ als, const float* __restrict__ ald,
    const float* __restrict__ selfa, const float* __restrict__ rel_alpha,
    const int* __restrict__ rowptr, const int* __restrict__ src_pk,
    const float* __restrict__ b1, const float* __restrict__ g1, const float* __restrict__ beta1,
    ushort_t* __restrict__ out, int N) {
    __shared__ float sh_rel[NREL * NHEAD];
    __shared__ float sh_aw[4][64 * NHEAD];   // per-wave [edge][head]
    __shared__ unsigned sh_off[4][64];       // per-wave row byte offsets
    int w = threadIdx.x >> 6, l = threadIdx.x & 63;
    if (threadIdx.x < NREL * NHEAD) sh_rel[threadIdx.x] = rel_alpha[threadIdx.x];
    __syncthreads();  // only barrier: publish sh_rel
    int i = blockIdx.x * 4 + w;
    if (i >= N) return;
    int hd = l >> 3;
    int sub = l & 7;
    float m = leaky(als[i * NHEAD + hd] + ald[i * NHEAD + hd] + selfa[i * NHEAD + hd]);
    float s = 1.0f;
    float ald_stage = ald[i * NHEAD + sub];
    float acc0, acc1, acc2, acc3;
    {
        u16x4 v = *reinterpret_cast<const u16x4*>(h1b + (size_t)i * HID + 4 * l);
        acc0 = b2f(v[0]); acc1 = b2f(v[1]); acc2 = b2f(v[2]); acc3 = b2f(v[3]);
    }
    int base = rowptr[i];
    int deg = rowptr[i + 1] - base;
    const char* hb = reinterpret_cast<const char*>(h1b);
    for (int cs = 0; cs < deg; cs += 64) {
        int c = min(64, deg - cs);
        for (int p = 0; p * 8 < c; p++) {
            int e = p * 8 + (l >> 3);
            if (e < c) {
                int pk = src_pk[base + cs + e];
                int sv = pk & 0xFFFFFF;
                int tv = (unsigned)pk >> 24;
                float a = als[sv * NHEAD + sub] + ald_stage + sh_rel[tv * NHEAD + sub];
                sh_aw[w][e * NHEAD + sub] = leaky(a);
                if (sub == 0) sh_off[w][e] = (unsigned)sv * (HID * 2);
            }
        }
        float cm = -1e30f;
        for (int e = sub; e < c; e += 8) cm = fmaxf(cm, sh_aw[w][e * NHEAD + hd]);
        for (int o = 1; o < 8; o <<= 1) cm = fmaxf(cm, __shfl_xor(cm, o, 64));
        float nm = fmaxf(m, cm);
        float f = __expf(m - nm);
        float csum = 0.f;
        for (int e = sub; e < c; e += 8) {
            float ww = __expf(sh_aw[w][e * NHEAD + hd] - nm);
            sh_aw[w][e * NHEAD + hd] = ww;
            csum += ww;
        }
        for (int o = 1; o < 8; o <<= 1) csum += __shfl_xor(csum, o, 64);
        s = s * f + csum;
        m = nm;
        acc0 *= f; acc1 *= f; acc2 *= f; acc3 *= f;
        int e = 0;
        for (; e + 4 <= c; e += 4) {
            unsigned o0 = sh_off[w][e], o1 = sh_off[w][e + 1];
            unsigned o2 = sh_off[w][e + 2], o3 = sh_off[w][e + 3];
            float w0 = sh_aw[w][e * NHEAD + hd], w1 = sh_aw[w][(e + 1) * NHEAD + hd];
            float w2 = sh_aw[w][(e + 2) * NHEAD + hd], w3 = sh_aw[w][(e + 3) * NHEAD + hd];
            u16x4 v0 = *reinterpret_cast<const u16x4*>(hb + o0 + 8 * l);
            u16x4 v1 = *reinterpret_cast<const u16x4*>(hb + o1 + 8 * l);
            u16x4 v2 = *reinterpret_cast<const u16x4*>(hb + o2 + 8 * l);
            u16x4 v3 = *reinterpret_cast<const u16x4*>(hb + o3 + 8 * l);
            acc0 += w0 * b2f(v0[0]) + w1 * b2f(v1[0]) + w2 * b2f(v2[0]) + w3 * b2f(v3[0]);
            acc1 += w0 * b2f(v0[1]) + w1 * b2f(v1[1]) + w2 * b2f(v2[1]) + w3 * b2f(v3[1]);
            acc2 += w0 * b2f(v0[2]) + w1 * b2f(v1[2]) + w2 * b2f(v2[2]) + w3 * b2f(v3[2]);
            acc3 += w0 * b2f(v0[3]) + w1 * b2f(v1[3]) + w2 * b2f(v2[3]) + w3 * b2f(v3[3]);
        }
        for (; e < c; e++) {
            unsigned o0 = sh_off[w][e];
            float w0 = sh_aw[w][e * NHEAD + hd];
            u16x4 v0 = *reinterpret_cast<const u16x4*>(hb + o0 + 8 * l);
            acc0 += w0 * b2f(v0[0]); acc1 += w0 * b2f(v0[1]);
            acc2 += w0 * b2f(v0[2]); acc3 += w0 * b2f(v0[3]);
        }
    }
    float inv = 1.0f / (s + 1e-16f);
    float4 bb = *reinterpret_cast<const float4*>(b1 + 4 * l);
    float y0 = acc0 * inv + bb.x, y1 = acc1 * inv + bb.y;
    float y2 = acc2 * inv + bb.z, y3 = acc3 * inv + bb.w;
    float su = y0 + y1 + y2 + y3;
    float sq = y0 * y0 + y1 * y1 + y2 * y2 + y3 * y3;
    for (int o = 1; o < 64; o <<= 1) {
        su += __shfl_xor(su, o, 64);
        sq += __shfl_xor(sq, o, 64);
    }
    float mean = su * (1.f / 256.f);
    float var = sq * (1.f / 256.f) - mean * mean;
    float rstd = rsqrtf(var + 1e-5f);
    float4 gg = *reinterpret_cast<const float4*>(g1 + 4 * l);
    float4 be = *reinterpret_cast<const float4*>(beta1 + 4 * l);
    float z0 = (y0 - mean) * rstd * gg.x + be.x;
    float z1 = (y1 - mean) * rstd * gg.y + be.y;
    float z2 = (y2 - mean) * rstd * gg.z + be.z;
    float z3 = (y3 - mean) * rstd * gg.w + be.w;
    u16x4 ov;
    ov[0] = f2bf(z0 > 0.f ? z0 : __expf(z0) - 1.f);
    ov[1] = f2bf(z1 > 0.f ? z1 : __expf(z1) - 1.f);
    ov[2] = f2bf(z2 > 0.f ? z2 : __expf(z2) - 1.f);
    ov[3] = f2bf(z3 > 0.f ? z3 : __expf(z3) - 1.f);
    *reinterpret_cast<u16x4*>(out + (size_t)i * HID + 4 * l) = ov;
}

// ---------------- per-node attention scalars, layer 2 (1 head, bf16 h2) ----------------
__global__ void __launch_bounds__(128) alpha2_kernel(const ushort_t* __restrict__ h2b,
                                                     const float* __restrict__ att_s,
                                                     const float* __restrict__ att_d,
                                                     float* __restrict__ als, float* __restrict__ ald) {
    int i = blockIdx.x, t = threadIdx.x;
    float v = b2f(h2b[(size_t)i * OUT_DIM + t]);
    float ps = v * att_s[t], pd = v * att_d[t];
    for (int o = 32; o > 0; o >>= 1) {
        ps += __shfl_xor(ps, o, 64);
        pd += __shfl_xor(pd, o, 64);
    }
    __shared__ float r0[2], r1[2];
    if ((t & 63) == 0) {
        r0[t >> 6] = ps;
        r1[t >> 6] = pd;
    }
    __syncthreads();
    if (t == 0) {
        als[i] = r0[0] + r0[1];
        ald[i] = r1[0] + r1[1];
    }
}

// ---------------- fused layer-2 aggregation: ONE WAVE PER NODE ----------------
__global__ void __launch_bounds__(256) node_agg2(const ushort_t* __restrict__ h2b,
                                                 const float* __restrict__ als,
                                                 const float* __restrict__ ald,
                                                 const int* __restrict__ rowptr,
                                                 const int* __restrict__ src_pk,
                                                 const float* __restrict__ b2,
                                                 const float* __restrict__ g2,
                                                 const float* __restrict__ beta2,
                                                 float* __restrict__ out, int N) {
    __shared__ float sh_a[4][64];
    __shared__ unsigned sh_off[4][64];
    int w = threadIdx.x >> 6, l = threadIdx.x & 63;
    int i = blockIdx.x * 4 + w;
    if (i >= N) return;
    float aldi = ald[i];
    float m = leaky(als[i] + aldi);
    float s = 1.0f;
    float acc0, acc1;
    {
        u16x2 v = *reinterpret_cast<const u16x2*>(h2b + (size_t)i * OUT_DIM + 2 * l);
        acc0 = b2f(v[0]); acc1 = b2f(v[1]);
    }
    int base = rowptr[i];
    int deg = rowptr[i + 1] - base;
    const char* hb = reinterpret_cast<const char*>(h2b);
    for (int cs = 0; cs < deg; cs += 64) {
        int c = min(64, deg - cs);
        float a = -1e30f;
        if (l < c) {
            int sv = src_pk[base + cs + l] & 0xFFFFFF;
            a = leaky(als[sv] + aldi);
            sh_off[w][l] = (unsigned)sv * (OUT_DIM * 2);
        }
        float cm = a;
        for (int o = 1; o < 64; o <<= 1) cm = fmaxf(cm, __shfl_xor(cm, o, 64));
        float nm = fmaxf(m, cm);
        float f = __expf(m - nm);
        float ww = (l < c) ? __expf(a - nm) : 0.f;
        sh_a[w][l] = ww;
        float csum = ww;
        for (int o = 1; o < 64; o <<= 1) csum += __shfl_xor(csum, o, 64);
        s = s * f + csum;
        m = nm;
        acc0 *= f; acc1 *= f;
        int e = 0;
        for (; e + 4 <= c; e += 4) {
            unsigned o0 = sh_off[w][e], o1 = sh_off[w][e + 1];
            unsigned o2 = sh_off[w][e + 2], o3 = sh_off[w][e + 3];
            float w0 = sh_a[w][e], w1 = sh_a[w][e + 1];
            float w2 = sh_a[w][e + 2], w3 = sh_a[w][e + 3];
            u16x2 v0 = *reinterpret_cast<const u16x2*>(hb + o0 + 4 * l);
            u16x2 v1 = *reinterpret_cast<const u16x2*>(hb + o1 + 4 * l);
            u16x2 v2 = *reinterpret_cast<const u16x2*>(hb + o2 + 4 * l);
            u16x2 v3 = *reinterpret_cast<const u16x2*>(hb + o3 + 4 * l);
            acc0 += w0 * b2f(v0[0]) + w1 * b2f(v1[0]) + w2 * b2f(v2[0]) + w3 * b2f(v3[0]);
            acc1 += w0 * b2f(v0[1]) + w1 * b2f(v1[1]) + w2 * b2f(v2[1]) + w3 * b2f(v3[1]);
        }
        for (; e < c; e++) {
            unsigned o0 = sh_off[w][e];
            float w0 = sh_a[w][e];
            u16x2 v0 = *reinterpret_cast<const u16x2*>(hb + o0 + 4 * l);
            acc0 += w0 * b2f(v0[0]); acc1 += w0 * b2f(v0[1]);
        }
    }
    float inv = 1.0f / (s + 1e-16f);
    float2 bb = *reinterpret_cast<const float2*>(b2 + 2 * l);
    float y0 = acc0 * inv + bb.x, y1 = acc1 * inv + bb.y;
    float su = y0 + y1, sq = y0 * y0 + y1 * y1;
    for (int o = 1; o < 64; o <<= 1) {
        su += __shfl_xor(su, o, 64);
        sq += __shfl_xor(sq, o, 64);
    }
    float mean = su * (1.f / 128.f);
    float var = sq * (1.f / 128.f) - mean * mean;
    float rstd = rsqrtf(var + 1e-5f);
    float2 gg = *reinterpret_cast<const float2*>(g2 + 2 * l);
    float2 be = *reinterpret_cast<const float2*>(beta2 + 2 * l);
    float2 ov;
    ov.x = (y0 - mean) * rstd * gg.x + be.x;
    ov.y = (y1 - mean) * rstd * gg.y + be.y;
    *reinterpret_cast<float2*>(out + (size_t)i * OUT_DIM + 2 * l) = ov;
}

extern "C" void kernel_launch(void* const* d_in, const int* in_sizes, int n_in,
                              void* d_out, int out_size, void* d_ws, size_t ws_size,
                              hipStream_t stream) {
    const float* x = (const float*)d_in[0];
    const int* ei = (const int*)d_in[1];
    const int* ety = (const int*)d_in[2];
    const float* rel_emb = (const float*)d_in[3];
    const float* W1 = (const float*)d_in[4];
    const float* att_s1 = (const float*)d_in[5];
    const float* att_d1 = (const float*)d_in[6];
    const float* We1 = (const float*)d_in[7];
    const float* att_e1 = (const float*)d_in[8];
    const float* b1 = (const float*)d_in[9];
    const float* g1 = (const float*)d_in[10];
    const float* beta1 = (const float*)d_in[11];
    const float* W2 = (const float*)d_in[12];
    const float* att_s2 = (const float*)d_in[13];
    const float* att_d2 = (const float*)d_in[14];
    const float* b2 = (const float*)d_in[15];
    const float* g2 = (const float*)d_in[16];
    const float* beta2 = (const float*)d_in[17];

    int N = in_sizes[0] / IN_DIM;
    int E = in_sizes[1] / 2;
    int Mpad = ((N + 127) / 128) * 128;
    const int* src0 = ei;
    const int* dst0 = ei + E;

    char* ws = (char*)d_ws;
    size_t off = 0;
    auto alloc = [&](size_t bytes) -> void* {
        off = (off + 255) & ~(size_t)255;
        void* p = ws + off;
        off += bytes;
        return p;
    };
    int* deg = (int*)alloc((size_t)N * 4);
    int* relcnt = (int*)alloc((size_t)N * NREL * 4);
    int* fill = (int*)alloc((size_t)N * 4);
    int* rowptr = (int*)alloc((size_t)(N + 1) * 4);
    int* src_pk = (int*)alloc((size_t)E * 4);
    float* rel_alpha = (float*)alloc(NREL * NHEAD * 4);
    float* als1 = (float*)alloc((size_t)N * NHEAD * 4);
    float* ald1 = (float*)alloc((size_t)N * NHEAD * 4);
    float* selfa = (float*)alloc((size_t)N * NHEAD * 4);
    float* al2s = (float*)alloc((size_t)N * 4);
    float* al2d = (float*)alloc((size_t)N * 4);
    ushort_t* W1t = (ushort_t*)alloc((size_t)HID * IN_DIM * 2);
    ushort_t* W2t = (ushort_t*)alloc((size_t)OUT_DIM * HID * 2);
    ushort_t* h1b = (ushort_t*)alloc((size_t)Mpad * HID * 2);
    ushort_t* xb = (ushort_t*)alloc((size_t)Mpad * IN_DIM * 2);
    // h1pb ALIASES xb: xb is dead after gemm1; h1pb live only from node_agg1 onward.
    ushort_t* h1pb = xb;
    ushort_t* h2b = h1b;  // h1b dead after node_agg1 -> reuse for layer-2 features

    hipMemsetAsync(deg, 0, (size_t)N * 4, stream);
    hipMemsetAsync(relcnt, 0, (size_t)N * NREL * 4, stream);
    hipMemsetAsync(fill, 0, (size_t)N * 4, stream);

    int eb = (E + 255) / 256;
    count_kernel<<<eb, 256, 0, stream>>>(dst0, ety, deg, relcnt, E);
    scan_kernel<<<1, 1024, 0, stream>>>(deg, rowptr, N);
    scatter_kernel<<<eb, 256, 0, stream>>>(src0, dst0, ety, rowptr, fill, src_pk, E);
    rel_alpha_kernel<<<1, 64, 0, stream>>>(rel_emb, We1, att_e1, rel_alpha);
    transpose_conv<<<(IN_DIM * HID + 255) / 256, 256, 0, stream>>>(W1, W1t, IN_DIM, HID);
    transpose_conv<<<(HID * OUT_DIM + 255) / 256, 256, 0, stream>>>(W2, W2t, HID, OUT_DIM);
    conv_bf16<<<2048, 256, 0, stream>>>(x, xb, N * IN_DIM, Mpad * IN_DIM);

    int NB1 = HID / 128;
    int T1 = (Mpad / 128) * NB1;
    gemm_lds<<<T1, 256, 0, stream>>>(xb, W1t, h1b, IN_DIM, HID, NB1);
    // xb dead now; zero h1pb tail rows [N, Mpad) (aliased region) before gemm2 reads them
    hipMemsetAsync(h1pb + (size_t)N * HID, 0, (size_t)(Mpad - N) * HID * 2, stream);
    alpha1_kernel<<<N, 256, 0, stream>>>(h1b, att_s1, att_d1, relcnt, deg, rel_alpha, als1, ald1, selfa);
    node_agg1<<<(N + 3) / 4, 256, 0, stream>>>(h1b, als1, ald1, selfa, rel_alpha, rowptr, src_pk,
                                               b1, g1, beta1, h1pb, N);

    int NB2 = OUT_DIM / 128;
    int T2 = (Mpad / 128) * NB2;
    gemm_lds<<<T2, 256, 0, stream>>>(h1pb, W2t, h2b, HID, OUT_DIM, NB2);
    alpha2_kernel<<<N, 128, 0, stream>>>(h2b, att_s2, att_d2, al2s, al2d);
    node_agg2<<<(N + 3) / 4, 256, 0, stream>>>(h2b, al2s, al2d, rowptr, src_pk, b2, g2, beta2,
                                               (float*)d_out, N);
}

// Round 8
// 422.666 us; speedup vs baseline: 1.2632x; 1.2132x over previous
//
#include <hip/hip_runtime.h>
#include <hip/hip_bf16.h>

#define IN_DIM 768
#define HID 256
#define OUT_DIM 128
#define NHEAD 8
#define NREL 6
#define RD 64

typedef unsigned short ushort_t;
typedef float f32x4 __attribute__((ext_vector_type(4)));
typedef __bf16 bf16x8 __attribute__((ext_vector_type(8)));
typedef unsigned short u16x8 __attribute__((ext_vector_type(8)));
typedef unsigned short u16x4 __attribute__((ext_vector_type(4)));
typedef unsigned short u16x2 __attribute__((ext_vector_type(2)));

typedef const __attribute__((address_space(1))) void* gptr_t;
typedef __attribute__((address_space(3))) void* lptr_t;

static __device__ __forceinline__ float leaky(float x) { return x > 0.f ? x : 0.2f * x; }

static __device__ __forceinline__ ushort_t f2bf(float f) {
    union { __hip_bfloat16 h; ushort_t u; } c;
    c.h = __float2bfloat16(f);
    return c.u;
}

static __device__ __forceinline__ float b2f(ushort_t u) {
    union { unsigned int i; float f; } c;
    c.i = ((unsigned int)u) << 16;
    return c.f;
}

// ---------------- CSR build ----------------
__global__ void count_kernel(const int* __restrict__ dst0, const int* __restrict__ ety,
                             int* __restrict__ deg, int* __restrict__ relcnt, int E) {
    int e = blockIdx.x * blockDim.x + threadIdx.x;
    if (e >= E) return;
    int d = dst0[e];
    atomicAdd(&deg[d], 1);
    atomicAdd(&relcnt[d * NREL + ety[e]], 1);
}

// ---- 3-kernel wide scan: A) per-1024-chunk sums  B) scan chunk sums  C) expand ----
__global__ void __launch_bounds__(256) scanA(const int* __restrict__ deg,
                                             int* __restrict__ bsum, int n) {
    __shared__ int sh[4];
    int b = blockIdx.x, t = threadIdx.x;
    int s = 0;
#pragma unroll
    for (int j = 0; j < 4; j++) {
        int idx = b * 1024 + t * 4 + j;
        if (idx < n) s += deg[idx];
    }
    for (int o = 32; o > 0; o >>= 1) s += __shfl_xor(s, o, 64);
    if ((t & 63) == 0) sh[t >> 6] = s;
    __syncthreads();
    if (t == 0) bsum[b] = sh[0] + sh[1] + sh[2] + sh[3];
}

__global__ void __launch_bounds__(256) scanB(const int* __restrict__ bsum,
                                             int* __restrict__ bbase,
                                             int* __restrict__ rowptr, int nb, int n) {
    __shared__ int sh[256];
    int t = threadIdx.x;
    int v = (t < nb) ? bsum[t] : 0;
    sh[t] = v;
    __syncthreads();
    for (int o = 1; o < 256; o <<= 1) {
        int add = (t >= o) ? sh[t - o] : 0;
        __syncthreads();
        sh[t] += add;
        __syncthreads();
    }
    if (t < nb) bbase[t] = sh[t] - v;
    if (t == 255) rowptr[n] = sh[255];
}

__global__ void __launch_bounds__(256) scanC(const int* __restrict__ deg,
                                             const int* __restrict__ bbase,
                                             int* __restrict__ rowptr, int n) {
    __shared__ int sh[256];
    int b = blockIdx.x, t = threadIdx.x;
    int base = b * 1024;
    int loc[4];
    int run = 0;
#pragma unroll
    for (int j = 0; j < 4; j++) {
        int idx = base + t * 4 + j;
        int d = (idx < n) ? deg[idx] : 0;
        loc[j] = run;
        run += d;
    }
    int tot = run;
    sh[t] = run;
    __syncthreads();
    for (int o = 1; o < 256; o <<= 1) {
        int add = (t >= o) ? sh[t - o] : 0;
        __syncthreads();
        sh[t] += add;
        __syncthreads();
    }
    int texcl = sh[t] - tot;
    int bb = bbase[b];
#pragma unroll
    for (int j = 0; j < 4; j++) {
        int idx = base + t * 4 + j;
        if (idx < n) rowptr[idx] = bb + texcl + loc[j];
    }
}

// packs src | (type<<24) into one word
__global__ void scatter_kernel(const int* __restrict__ src0, const int* __restrict__ dst0,
                               const int* __restrict__ ety, const int* __restrict__ rowptr,
                               int* __restrict__ fill, int* __restrict__ src_pk, int E) {
    int e = blockIdx.x * blockDim.x + threadIdx.x;
    if (e >= E) return;
    int d = dst0[e];
    int pos = rowptr[d] + atomicAdd(&fill[d], 1);
    src_pk[pos] = src0[e] | (ety[e] << 24);
}

// rel_alpha[r][h] = sum_c (rel_emb[r] @ We1)[h*32+c] * att_e1[h][c]
__global__ void rel_alpha_kernel(const float* __restrict__ rel_emb, const float* __restrict__ We1,
                                 const float* __restrict__ att_e1, float* __restrict__ rel_alpha) {
    int t = threadIdx.x;
    if (t >= NREL * NHEAD) return;
    int r = t / NHEAD, h = t % NHEAD;
    float acc = 0.f;
    for (int c = 0; c < HID / NHEAD; c++) {
        float v = 0.f;
        for (int k = 0; k < RD; k++) v += rel_emb[r * RD + k] * We1[k * HID + h * 32 + c];
        acc += v * att_e1[h * 32 + c];
    }
    rel_alpha[r * NHEAD + h] = acc;
}

// selfa[i][h] = (relcnt[i] . rel_alpha[:,h]) / max(deg,1)   (32 nodes/block)
__global__ void __launch_bounds__(256) selfa_kernel(const int* __restrict__ relcnt,
                                                    const int* __restrict__ deg,
                                                    const float* __restrict__ rel_alpha,
                                                    float* __restrict__ selfa, int N) {
    __shared__ float sra[NREL * NHEAD];
    int t = threadIdx.x;
    if (t < NREL * NHEAD) sra[t] = rel_alpha[t];
    __syncthreads();
    int i = blockIdx.x * 32 + (t >> 3);
    int h = t & 7;
    if (i >= N) return;
    float dv = fmaxf((float)deg[i], 1.0f);
    float acc = 0.f;
#pragma unroll
    for (int r = 0; r < NREL; r++) acc += (float)relcnt[i * NREL + r] * sra[r * NHEAD + h];
    selfa[i * NHEAD + h] = acc / dv;
}

// W[K][Nc] fp32 -> Wt[Nc][K] bf16
__global__ void transpose_conv(const float* __restrict__ W, ushort_t* __restrict__ Wt,
                               int K, int Nc) {
    int i = blockIdx.x * 256 + threadIdx.x;
    if (i >= K * Nc) return;
    int k = i / Nc, n = i % Nc;
    Wt[n * K + k] = f2bf(W[i]);
}

// x fp32 -> xb bf16 (rows [N,Mpad) zeroed)
__global__ void __launch_bounds__(256) conv_bf16(const float* __restrict__ x,
                                                 ushort_t* __restrict__ xb,
                                                 int total, int padtotal) {
    for (long long idx = (long long)(blockIdx.x * 256 + threadIdx.x) * 8; idx < padtotal;
         idx += (long long)gridDim.x * 256 * 8) {
        u16x8 o;
        if (idx < total) {
            float4 f0 = *reinterpret_cast<const float4*>(x + idx);
            float4 f1 = *reinterpret_cast<const float4*>(x + idx + 4);
            o[0] = f2bf(f0.x); o[1] = f2bf(f0.y); o[2] = f2bf(f0.z); o[3] = f2bf(f0.w);
            o[4] = f2bf(f1.x); o[5] = f2bf(f1.y); o[6] = f2bf(f1.z); o[7] = f2bf(f1.w);
        } else {
            o = u16x8{0, 0, 0, 0, 0, 0, 0, 0};
        }
        *reinterpret_cast<u16x8*>(xb + idx) = o;
    }
}

// ---------------- MFMA bf16 GEMM (m97 structure) + fused attention-scalar epilogue -------------
// AMODE 1 (gemm1, Nout=256): each (row, head) owned by one wave -> plain stores of
//   als[row*8+h]/ald[row*8+h] after 16-lane shfl column-reduce.
// AMODE 2 (gemm2, Nout=128, NBlk=1): block holds full rows; 2 waves/row -> LDS combine,
//   stores als[row]/ald[row].
template <int AMODE>
__global__ void __launch_bounds__(256) gemm_lds(const ushort_t* __restrict__ A,
                                                const ushort_t* __restrict__ Bt,
                                                ushort_t* __restrict__ C,
                                                int K, int Nout, int NBlk,
                                                const float* __restrict__ att_s,
                                                const float* __restrict__ att_d,
                                                float* __restrict__ als,
                                                float* __restrict__ ald, int N) {
    __shared__ ushort_t sA[128 * 64];
    __shared__ ushort_t sB[128 * 64];
    int T = gridDim.x;
    int p = blockIdx.x;
    int q8 = T >> 3, rr8 = T & 7, xc = p & 7, j = p >> 3;
    int l = (xc < rr8 ? xc * (q8 + 1) : rr8 * (q8 + 1) + (xc - rr8) * q8) + j;
    int m0 = (l / NBlk) * 128;
    int n0 = (l % NBlk) * 128;
    int t = threadIdx.x;
    int w = t >> 6, ln = t & 63;
    int wm = (w >> 1) * 64, wn = (w & 1) * 64;

    const ushort_t* ag = A + (size_t)(m0 + w * 32 + (ln >> 3)) * K + (ln & 7) * 8;
    const ushort_t* bg = Bt + (size_t)(n0 + w * 32 + (ln >> 3)) * K + (ln & 7) * 8;

    f32x4 acc[4][4] = {};

    for (int k0 = 0; k0 < K; k0 += 64) {
#pragma unroll
        for (int i = 0; i < 4; i++) {
            __builtin_amdgcn_global_load_lds(
                (gptr_t)(const void*)(ag + (size_t)i * 8 * K + k0),
                (lptr_t)(void*)(&sA[(w * 32 + i * 8) * 64]), 16, 0, 0);
            __builtin_amdgcn_global_load_lds(
                (gptr_t)(const void*)(bg + (size_t)i * 8 * K + k0),
                (lptr_t)(void*)(&sB[(w * 32 + i * 8) * 64]), 16, 0, 0);
        }
        __syncthreads();
#pragma unroll
        for (int ks = 0; ks < 2; ks++) {
            bf16x8 af[4], bfr[4];
#pragma unroll
            for (int m = 0; m < 4; m++)
                af[m] = *reinterpret_cast<const bf16x8*>(
                    &sA[(wm + m * 16 + (ln & 15)) * 64 + ks * 32 + (ln >> 4) * 8]);
#pragma unroll
            for (int n = 0; n < 4; n++)
                bfr[n] = *reinterpret_cast<const bf16x8*>(
                    &sB[(wn + n * 16 + (ln & 15)) * 64 + ks * 32 + (ln >> 4) * 8]);
#pragma unroll
            for (int m = 0; m < 4; m++)
#pragma unroll
                for (int n = 0; n < 4; n++)
                    acc[m][n] = __builtin_amdgcn_mfma_f32_16x16x32_bf16(af[m], bfr[n], acc[m][n], 0, 0, 0);
        }
        __syncthreads();
    }

    int cc = ln & 15, qq = ln >> 4;
#pragma unroll
    for (int m = 0; m < 4; m++) {
#pragma unroll
        for (int rr = 0; rr < 4; rr++) {
            int row = m0 + wm + m * 16 + qq * 4 + rr;
#pragma unroll
            for (int n = 0; n < 4; n++)
                C[(size_t)row * Nout + n0 + wn + n * 16 + cc] = f2bf(acc[m][n][rr]);
        }
    }

    float as_[4], ad_[4];
#pragma unroll
    for (int n = 0; n < 4; n++) {
        int col = n0 + wn + n * 16 + cc;
        as_[n] = att_s[col];
        ad_[n] = att_d[col];
    }

    if constexpr (AMODE == 1) {
        int hbase = (n0 + wn) >> 5;
#pragma unroll
        for (int m = 0; m < 4; m++) {
#pragma unroll
            for (int rr = 0; rr < 4; rr++) {
                int row = m0 + wm + m * 16 + qq * 4 + rr;
                float ps0 = acc[m][0][rr] * as_[0] + acc[m][1][rr] * as_[1];
                float ps1 = acc[m][2][rr] * as_[2] + acc[m][3][rr] * as_[3];
                float pd0 = acc[m][0][rr] * ad_[0] + acc[m][1][rr] * ad_[1];
                float pd1 = acc[m][2][rr] * ad_[2] + acc[m][3][rr] * ad_[3];
#pragma unroll
                for (int o = 1; o < 16; o <<= 1) {
                    ps0 += __shfl_xor(ps0, o, 64);
                    ps1 += __shfl_xor(ps1, o, 64);
                    pd0 += __shfl_xor(pd0, o, 64);
                    pd1 += __shfl_xor(pd1, o, 64);
                }
                if (cc == 0 && row < N) {
                    als[row * NHEAD + hbase] = ps0;
                    als[row * NHEAD + hbase + 1] = ps1;
                    ald[row * NHEAD + hbase] = pd0;
                    ald[row * NHEAD + hbase + 1] = pd1;
                }
            }
        }
    } else {
        __shared__ float sh_s[2][128];
        __shared__ float sh_d[2][128];
#pragma unroll
        for (int m = 0; m < 4; m++) {
#pragma unroll
            for (int rr = 0; rr < 4; rr++) {
                int rib = wm + m * 16 + qq * 4 + rr;
                float ps = acc[m][0][rr] * as_[0] + acc[m][1][rr] * as_[1] +
                           acc[m][2][rr] * as_[2] + acc[m][3][rr] * as_[3];
                float pd = acc[m][0][rr] * ad_[0] + acc[m][1][rr] * ad_[1] +
                           acc[m][2][rr] * ad_[2] + acc[m][3][rr] * ad_[3];
#pragma unroll
                for (int o = 1; o < 16; o <<= 1) {
                    ps += __shfl_xor(ps, o, 64);
                    pd += __shfl_xor(pd, o, 64);
                }
                if (cc == 0) {
                    sh_s[wn >> 6][rib] = ps;
                    sh_d[wn >> 6][rib] = pd;
                }
            }
        }
        __syncthreads();
        if (t < 128) {
            int row = m0 + t;
            if (row < N) {
                als[row] = sh_s[0][t] + sh_s[1][t];
                ald[row] = sh_d[0][t] + sh_d[1][t];
            }
        }
    }
}

// ---------------- fused layer-1 aggregation: ONE WAVE PER NODE ----------------
__global__ void __launch_bounds__(256) node_agg1(
    const ushort_t* __restrict__ h1b, const float* __restrict__ als, const float* __restrict__ ald,
    const float* __restrict__ selfa, const float* __restrict__ rel_alpha,
    const int* __restrict__ rowptr, const int* __restrict__ src_pk,
    const float* __restrict__ b1, const float* __restrict__ g1, const float* __restrict__ beta1,
    ushort_t* __restrict__ out, int N) {
    __shared__ float sh_rel[NREL * NHEAD];
    __shared__ float sh_aw[4][64 * NHEAD];
    __shared__ unsigned sh_off[4][64];
    int w = threadIdx.x >> 6, l = threadIdx.x & 63;
    if (threadIdx.x < NREL * NHEAD) sh_rel[threadIdx.x] = rel_alpha[threadIdx.x];
    __syncthreads();
    int i = blockIdx.x * 4 + w;
    if (i >= N) return;
    int hd = l >> 3;
    int sub = l & 7;
    float m = leaky(als[i * NHEAD + hd] + ald[i * NHEAD + hd] + selfa[i * NHEAD + hd]);
    float s = 1.0f;
    float ald_stage = ald[i * NHEAD + sub];
    float acc0, acc1, acc2, acc3;
    {
        u16x4 v = *reinterpret_cast<const u16x4*>(h1b + (size_t)i * HID + 4 * l);
        acc0 = b2f(v[0]); acc1 = b2f(v[1]); acc2 = b2f(v[2]); acc3 = b2f(v[3]);
    }
    int base = rowptr[i];
    int deg = rowptr[i + 1] - base;
    const char* hb = reinterpret_cast<const char*>(h1b);
    for (int cs = 0; cs < deg; cs += 64) {
        int c = min(64, deg - cs);
        for (int p = 0; p * 8 < c; p++) {
            int e = p * 8 + (l >> 3);
            if (e < c) {
                int pk = src_pk[base + cs + e];
                int sv = pk & 0xFFFFFF;
                int tv = (unsigned)pk >> 24;
                float a = als[sv * NHEAD + sub] + ald_stage + sh_rel[tv * NHEAD + sub];
                sh_aw[w][e * NHEAD + sub] = leaky(a);
                if (sub == 0) sh_off[w][e] = (unsigned)sv * (HID * 2);
            }
        }
        float cm = -1e30f;
        for (int e = sub; e < c; e += 8) cm = fmaxf(cm, sh_aw[w][e * NHEAD + hd]);
        for (int o = 1; o < 8; o <<= 1) cm = fmaxf(cm, __shfl_xor(cm, o, 64));
        float nm = fmaxf(m, cm);
        float f = __expf(m - nm);
        float csum = 0.f;
        for (int e = sub; e < c; e += 8) {
            float ww = __expf(sh_aw[w][e * NHEAD + hd] - nm);
            sh_aw[w][e * NHEAD + hd] = ww;
            csum += ww;
        }
        for (int o = 1; o < 8; o <<= 1) csum += __shfl_xor(csum, o, 64);
        s = s * f + csum;
        m = nm;
        acc0 *= f; acc1 *= f; acc2 *= f; acc3 *= f;
        int e = 0;
        for (; e + 8 <= c; e += 8) {
            unsigned ofs[8];
            float wt[8];
            u16x4 v[8];
#pragma unroll
            for (int jj = 0; jj < 8; jj++) {
                ofs[jj] = sh_off[w][e + jj];
                wt[jj] = sh_aw[w][(e + jj) * NHEAD + hd];
            }
#pragma unroll
            for (int jj = 0; jj < 8; jj++)
                v[jj] = *reinterpret_cast<const u16x4*>(hb + ofs[jj] + 8 * l);
#pragma unroll
            for (int jj = 0; jj < 8; jj++) {
                acc0 += wt[jj] * b2f(v[jj][0]);
                acc1 += wt[jj] * b2f(v[jj][1]);
                acc2 += wt[jj] * b2f(v[jj][2]);
                acc3 += wt[jj] * b2f(v[jj][3]);
            }
        }
        for (; e < c; e++) {
            unsigned o0 = sh_off[w][e];
            float w0 = sh_aw[w][e * NHEAD + hd];
            u16x4 v0 = *reinterpret_cast<const u16x4*>(hb + o0 + 8 * l);
            acc0 += w0 * b2f(v0[0]); acc1 += w0 * b2f(v0[1]);
            acc2 += w0 * b2f(v0[2]); acc3 += w0 * b2f(v0[3]);
        }
    }
    float inv = 1.0f / (s + 1e-16f);
    float4 bb = *reinterpret_cast<const float4*>(b1 + 4 * l);
    float y0 = acc0 * inv + bb.x, y1 = acc1 * inv + bb.y;
    float y2 = acc2 * inv + bb.z, y3 = acc3 * inv + bb.w;
    float su = y0 + y1 + y2 + y3;
    float sq = y0 * y0 + y1 * y1 + y2 * y2 + y3 * y3;
    for (int o = 1; o < 64; o <<= 1) {
        su += __shfl_xor(su, o, 64);
        sq += __shfl_xor(sq, o, 64);
    }
    float mean = su * (1.f / 256.f);
    float var = sq * (1.f / 256.f) - mean * mean;
    float rstd = rsqrtf(var + 1e-5f);
    float4 gg = *reinterpret_cast<const float4*>(g1 + 4 * l);
    float4 be = *reinterpret_cast<const float4*>(beta1 + 4 * l);
    float z0 = (y0 - mean) * rstd * gg.x + be.x;
    float z1 = (y1 - mean) * rstd * gg.y + be.y;
    float z2 = (y2 - mean) * rstd * gg.z + be.z;
    float z3 = (y3 - mean) * rstd * gg.w + be.w;
    u16x4 ov;
    ov[0] = f2bf(z0 > 0.f ? z0 : __expf(z0) - 1.f);
    ov[1] = f2bf(z1 > 0.f ? z1 : __expf(z1) - 1.f);
    ov[2] = f2bf(z2 > 0.f ? z2 : __expf(z2) - 1.f);
    ov[3] = f2bf(z3 > 0.f ? z3 : __expf(z3) - 1.f);
    *reinterpret_cast<u16x4*>(out + (size_t)i * HID + 4 * l) = ov;
}

// ---------------- fused layer-2 aggregation: ONE WAVE PER NODE ----------------
__global__ void __launch_bounds__(256) node_agg2(const ushort_t* __restrict__ h2b,
                                                 const float* __restrict__ als,
                                                 const float* __restrict__ ald,
                                                 const int* __restrict__ rowptr,
                                                 const int* __restrict__ src_pk,
                                                 const float* __restrict__ b2,
                                                 const float* __restrict__ g2,
                                                 const float* __restrict__ beta2,
                                                 float* __restrict__ out, int N) {
    __shared__ float sh_a[4][64];
    __shared__ unsigned sh_off[4][64];
    int w = threadIdx.x >> 6, l = threadIdx.x & 63;
    int i = blockIdx.x * 4 + w;
    if (i >= N) return;
    float aldi = ald[i];
    float m = leaky(als[i] + aldi);
    float s = 1.0f;
    float acc0, acc1;
    {
        u16x2 v = *reinterpret_cast<const u16x2*>(h2b + (size_t)i * OUT_DIM + 2 * l);
        acc0 = b2f(v[0]); acc1 = b2f(v[1]);
    }
    int base = rowptr[i];
    int deg = rowptr[i + 1] - base;
    const char* hb = reinterpret_cast<const char*>(h2b);
    for (int cs = 0; cs < deg; cs += 64) {
        int c = min(64, deg - cs);
        float a = -1e30f;
        if (l < c) {
            int sv = src_pk[base + cs + l] & 0xFFFFFF;
            a = leaky(als[sv] + aldi);
            sh_off[w][l] = (unsigned)sv * (OUT_DIM * 2);
        }
        float cm = a;
        for (int o = 1; o < 64; o <<= 1) cm = fmaxf(cm, __shfl_xor(cm, o, 64));
        float nm = fmaxf(m, cm);
        float f = __expf(m - nm);
        float ww = (l < c) ? __expf(a - nm) : 0.f;
        sh_a[w][l] = ww;
        float csum = ww;
        for (int o = 1; o < 64; o <<= 1) csum += __shfl_xor(csum, o, 64);
        s = s * f + csum;
        m = nm;
        acc0 *= f; acc1 *= f;
        int e = 0;
        for (; e + 8 <= c; e += 8) {
            unsigned ofs[8];
            float wt[8];
            u16x2 v[8];
#pragma unroll
            for (int jj = 0; jj < 8; jj++) {
                ofs[jj] = sh_off[w][e + jj];
                wt[jj] = sh_a[w][e + jj];
            }
#pragma unroll
            for (int jj = 0; jj < 8; jj++)
                v[jj] = *reinterpret_cast<const u16x2*>(hb + ofs[jj] + 4 * l);
#pragma unroll
            for (int jj = 0; jj < 8; jj++) {
                acc0 += wt[jj] * b2f(v[jj][0]);
                acc1 += wt[jj] * b2f(v[jj][1]);
            }
        }
        for (; e < c; e++) {
            unsigned o0 = sh_off[w][e];
            float w0 = sh_a[w][e];
            u16x2 v0 = *reinterpret_cast<const u16x2*>(hb + o0 + 4 * l);
            acc0 += w0 * b2f(v0[0]); acc1 += w0 * b2f(v0[1]);
        }
    }
    float inv = 1.0f / (s + 1e-16f);
    float2 bb = *reinterpret_cast<const float2*>(b2 + 2 * l);
    float y0 = acc0 * inv + bb.x, y1 = acc1 * inv + bb.y;
    float su = y0 + y1, sq = y0 * y0 + y1 * y1;
    for (int o = 1; o < 64; o <<= 1) {
        su += __shfl_xor(su, o, 64);
        sq += __shfl_xor(sq, o, 64);
    }
    float mean = su * (1.f / 128.f);
    float var = sq * (1.f / 128.f) - mean * mean;
    float rstd = rsqrtf(var + 1e-5f);
    float2 gg = *reinterpret_cast<const float2*>(g2 + 2 * l);
    float2 be = *reinterpret_cast<const float2*>(beta2 + 2 * l);
    float2 ov;
    ov.x = (y0 - mean) * rstd * gg.x + be.x;
    ov.y = (y1 - mean) * rstd * gg.y + be.y;
    *reinterpret_cast<float2*>(out + (size_t)i * OUT_DIM + 2 * l) = ov;
}

extern "C" void kernel_launch(void* const* d_in, const int* in_sizes, int n_in,
                              void* d_out, int out_size, void* d_ws, size_t ws_size,
                              hipStream_t stream) {
    const float* x = (const float*)d_in[0];
    const int* ei = (const int*)d_in[1];
    const int* ety = (const int*)d_in[2];
    const float* rel_emb = (const float*)d_in[3];
    const float* W1 = (const float*)d_in[4];
    const float* att_s1 = (const float*)d_in[5];
    const float* att_d1 = (const float*)d_in[6];
    const float* We1 = (const float*)d_in[7];
    const float* att_e1 = (const float*)d_in[8];
    const float* b1 = (const float*)d_in[9];
    const float* g1 = (const float*)d_in[10];
    const float* beta1 = (const float*)d_in[11];
    const float* W2 = (const float*)d_in[12];
    const float* att_s2 = (const float*)d_in[13];
    const float* att_d2 = (const float*)d_in[14];
    const float* b2 = (const float*)d_in[15];
    const float* g2 = (const float*)d_in[16];
    const float* beta2 = (const float*)d_in[17];

    int N = in_sizes[0] / IN_DIM;
    int E = in_sizes[1] / 2;
    int Mpad = ((N + 127) / 128) * 128;
    const int* src0 = ei;
    const int* dst0 = ei + E;

    char* ws = (char*)d_ws;
    size_t off = 0;
    auto alloc = [&](size_t bytes) -> void* {
        off = (off + 255) & ~(size_t)255;
        void* p = ws + off;
        off += bytes;
        return p;
    };
    int* deg = (int*)alloc((size_t)N * 4);
    int* relcnt = (int*)alloc((size_t)N * NREL * 4);
    int* fill = (int*)alloc((size_t)N * 4);
    int* rowptr = (int*)alloc((size_t)(N + 1) * 4);
    int* src_pk = (int*)alloc((size_t)E * 4);
    int nb = (N + 1023) >> 10;
    int* bsum = (int*)alloc((size_t)nb * 4);
    int* bbase = (int*)alloc((size_t)nb * 4);
    float* rel_alpha = (float*)alloc(NREL * NHEAD * 4);
    float* als1 = (float*)alloc((size_t)N * NHEAD * 4);
    float* ald1 = (float*)alloc((size_t)N * NHEAD * 4);
    float* selfa = (float*)alloc((size_t)N * NHEAD * 4);
    float* al2s = (float*)alloc((size_t)N * 4);
    float* al2d = (float*)alloc((size_t)N * 4);
    ushort_t* W1t = (ushort_t*)alloc((size_t)HID * IN_DIM * 2);
    ushort_t* W2t = (ushort_t*)alloc((size_t)OUT_DIM * HID * 2);
    ushort_t* h1b = (ushort_t*)alloc((size_t)Mpad * HID * 2);
    ushort_t* xb = (ushort_t*)alloc((size_t)Mpad * IN_DIM * 2);
    ushort_t* h1pb = xb;   // xb dead after gemm1
    ushort_t* h2b = h1b;   // h1b dead after node_agg1

    hipMemsetAsync(deg, 0, (size_t)N * 4, stream);
    hipMemsetAsync(relcnt, 0, (size_t)N * NREL * 4, stream);
    hipMemsetAsync(fill, 0, (size_t)N * 4, stream);

    int eb = (E + 255) / 256;
    count_kernel<<<eb, 256, 0, stream>>>(dst0, ety, deg, relcnt, E);
    scanA<<<nb, 256, 0, stream>>>(deg, bsum, N);
    scanB<<<1, 256, 0, stream>>>(bsum, bbase, rowptr, nb, N);
    scanC<<<nb, 256, 0, stream>>>(deg, bbase, rowptr, N);
    scatter_kernel<<<eb, 256, 0, stream>>>(src0, dst0, ety, rowptr, fill, src_pk, E);
    rel_alpha_kernel<<<1, 64, 0, stream>>>(rel_emb, We1, att_e1, rel_alpha);
    selfa_kernel<<<(N + 31) / 32, 256, 0, stream>>>(relcnt, deg, rel_alpha, selfa, N);
    transpose_conv<<<(IN_DIM * HID + 255) / 256, 256, 0, stream>>>(W1, W1t, IN_DIM, HID);
    transpose_conv<<<(HID * OUT_DIM + 255) / 256, 256, 0, stream>>>(W2, W2t, HID, OUT_DIM);
    conv_bf16<<<2048, 256, 0, stream>>>(x, xb, N * IN_DIM, Mpad * IN_DIM);

    int NB1 = HID / 128;
    int T1 = (Mpad / 128) * NB1;
    gemm_lds<1><<<T1, 256, 0, stream>>>(xb, W1t, h1b, IN_DIM, HID, NB1,
                                        att_s1, att_d1, als1, ald1, N);
    hipMemsetAsync(h1pb + (size_t)N * HID, 0, (size_t)(Mpad - N) * HID * 2, stream);
    node_agg1<<<(N + 3) / 4, 256, 0, stream>>>(h1b, als1, ald1, selfa, rel_alpha, rowptr, src_pk,
                                               b1, g1, beta1, h1pb, N);

    int NB2 = OUT_DIM / 128;
    int T2 = (Mpad / 128) * NB2;
    gemm_lds<2><<<T2, 256, 0, stream>>>(h1pb, W2t, h2b, HID, OUT_DIM, NB2,
                                        att_s2, att_d2, al2s, al2d, N);
    node_agg2<<<(N + 3) / 4, 256, 0, stream>>>(h2b, al2s, al2d, rowptr, src_pk, b2, g2, beta2,
                                               (float*)d_out, N);
}

// Round 9
// 371.946 us; speedup vs baseline: 1.4354x; 1.1364x over previous
//
#include <hip/hip_runtime.h>
#include <hip/hip_bf16.h>

#define IN_DIM 768
#define HID 256
#define OUT_DIM 128
#define NHEAD 8
#define NREL 6
#define RD 64

typedef unsigned short ushort_t;
typedef float f32x4 __attribute__((ext_vector_type(4)));
typedef __bf16 bf16x8 __attribute__((ext_vector_type(8)));
typedef unsigned short u16x8 __attribute__((ext_vector_type(8)));
typedef unsigned short u16x4 __attribute__((ext_vector_type(4)));
typedef unsigned short u16x2 __attribute__((ext_vector_type(2)));

typedef const __attribute__((address_space(1))) void* gptr_t;
typedef __attribute__((address_space(3))) void* lptr_t;

static __device__ __forceinline__ float leaky(float x) { return x > 0.f ? x : 0.2f * x; }

static __device__ __forceinline__ ushort_t f2bf(float f) {
    union { __hip_bfloat16 h; ushort_t u; } c;
    c.h = __float2bfloat16(f);
    return c.u;
}

static __device__ __forceinline__ float b2f(ushort_t u) {
    union { unsigned int i; float f; } c;
    c.i = ((unsigned int)u) << 16;
    return c.f;
}

// ---------------- CSR build ----------------
__global__ void count_kernel(const int* __restrict__ dst0, int* __restrict__ deg, int E) {
    int e = blockIdx.x * blockDim.x + threadIdx.x;
    if (e >= E) return;
    atomicAdd(&deg[dst0[e]], 1);
}

// ---- 3-kernel wide scan ----
__global__ void __launch_bounds__(256) scanA(const int* __restrict__ deg,
                                             int* __restrict__ bsum, int n) {
    __shared__ int sh[4];
    int b = blockIdx.x, t = threadIdx.x;
    int s = 0;
#pragma unroll
    for (int j = 0; j < 4; j++) {
        int idx = b * 1024 + t * 4 + j;
        if (idx < n) s += deg[idx];
    }
    for (int o = 32; o > 0; o >>= 1) s += __shfl_xor(s, o, 64);
    if ((t & 63) == 0) sh[t >> 6] = s;
    __syncthreads();
    if (t == 0) bsum[b] = sh[0] + sh[1] + sh[2] + sh[3];
}

__global__ void __launch_bounds__(256) scanB(const int* __restrict__ bsum,
                                             int* __restrict__ bbase,
                                             int* __restrict__ rowptr, int nb, int n) {
    __shared__ int sh[256];
    int t = threadIdx.x;
    int v = (t < nb) ? bsum[t] : 0;
    sh[t] = v;
    __syncthreads();
    for (int o = 1; o < 256; o <<= 1) {
        int add = (t >= o) ? sh[t - o] : 0;
        __syncthreads();
        sh[t] += add;
        __syncthreads();
    }
    if (t < nb) bbase[t] = sh[t] - v;
    if (t == 255) rowptr[n] = sh[255];
}

__global__ void __launch_bounds__(256) scanC(const int* __restrict__ deg,
                                             const int* __restrict__ bbase,
                                             int* __restrict__ rowptr, int n) {
    __shared__ int sh[256];
    int b = blockIdx.x, t = threadIdx.x;
    int base = b * 1024;
    int loc[4];
    int run = 0;
#pragma unroll
    for (int j = 0; j < 4; j++) {
        int idx = base + t * 4 + j;
        int d = (idx < n) ? deg[idx] : 0;
        loc[j] = run;
        run += d;
    }
    int tot = run;
    sh[t] = run;
    __syncthreads();
    for (int o = 1; o < 256; o <<= 1) {
        int add = (t >= o) ? sh[t - o] : 0;
        __syncthreads();
        sh[t] += add;
        __syncthreads();
    }
    int texcl = sh[t] - tot;
    int bb = bbase[b];
#pragma unroll
    for (int j = 0; j < 4; j++) {
        int idx = base + t * 4 + j;
        if (idx < n) rowptr[idx] = bb + texcl + loc[j];
    }
}

// packs src | (type<<24) into one word
__global__ void scatter_kernel(const int* __restrict__ src0, const int* __restrict__ dst0,
                               const int* __restrict__ ety, const int* __restrict__ rowptr,
                               int* __restrict__ fill, int* __restrict__ src_pk, int E) {
    int e = blockIdx.x * blockDim.x + threadIdx.x;
    if (e >= E) return;
    int d = dst0[e];
    int pos = rowptr[d] + atomicAdd(&fill[d], 1);
    src_pk[pos] = src0[e] | (ety[e] << 24);
}

// rel_alpha[r][h] = sum_c (rel_emb[r] @ We1)[h*32+c] * att_e1[h][c]
__global__ void rel_alpha_kernel(const float* __restrict__ rel_emb, const float* __restrict__ We1,
                                 const float* __restrict__ att_e1, float* __restrict__ rel_alpha) {
    int t = threadIdx.x;
    if (t >= NREL * NHEAD) return;
    int r = t / NHEAD, h = t % NHEAD;
    float acc = 0.f;
    for (int c = 0; c < HID / NHEAD; c++) {
        float v = 0.f;
        for (int k = 0; k < RD; k++) v += rel_emb[r * RD + k] * We1[k * HID + h * 32 + c];
        acc += v * att_e1[h * 32 + c];
    }
    rel_alpha[r * NHEAD + h] = acc;
}

// W[K][Nc] fp32 -> Wt[Nc][K] bf16
__global__ void transpose_conv(const float* __restrict__ W, ushort_t* __restrict__ Wt,
                               int K, int Nc) {
    int i = blockIdx.x * 256 + threadIdx.x;
    if (i >= K * Nc) return;
    int k = i / Nc, n = i % Nc;
    Wt[n * K + k] = f2bf(W[i]);
}

// x fp32 -> xb bf16 (rows [N,Mpad) zeroed)
__global__ void __launch_bounds__(256) conv_bf16(const float* __restrict__ x,
                                                 ushort_t* __restrict__ xb,
                                                 int total, int padtotal) {
    for (long long idx = (long long)(blockIdx.x * 256 + threadIdx.x) * 8; idx < padtotal;
         idx += (long long)gridDim.x * 256 * 8) {
        u16x8 o;
        if (idx < total) {
            float4 f0 = *reinterpret_cast<const float4*>(x + idx);
            float4 f1 = *reinterpret_cast<const float4*>(x + idx + 4);
            o[0] = f2bf(f0.x); o[1] = f2bf(f0.y); o[2] = f2bf(f0.z); o[3] = f2bf(f0.w);
            o[4] = f2bf(f1.x); o[5] = f2bf(f1.y); o[6] = f2bf(f1.z); o[7] = f2bf(f1.w);
        } else {
            o = u16x8{0, 0, 0, 0, 0, 0, 0, 0};
        }
        *reinterpret_cast<u16x8*>(xb + idx) = o;
    }
}

// ---------------- MFMA bf16 GEMM (m97 structure) + fused attention-scalar epilogue ------------
template <int AMODE>
__global__ void __launch_bounds__(256) gemm_lds(const ushort_t* __restrict__ A,
                                                const ushort_t* __restrict__ Bt,
                                                ushort_t* __restrict__ C,
                                                int K, int Nout, int NBlk,
                                                const float* __restrict__ att_s,
                                                const float* __restrict__ att_d,
                                                float* __restrict__ als,
                                                float* __restrict__ ald, int N) {
    __shared__ ushort_t sA[128 * 64];
    __shared__ ushort_t sB[128 * 64];
    int T = gridDim.x;
    int p = blockIdx.x;
    int q8 = T >> 3, rr8 = T & 7, xc = p & 7, j = p >> 3;
    int l = (xc < rr8 ? xc * (q8 + 1) : rr8 * (q8 + 1) + (xc - rr8) * q8) + j;
    int m0 = (l / NBlk) * 128;
    int n0 = (l % NBlk) * 128;
    int t = threadIdx.x;
    int w = t >> 6, ln = t & 63;
    int wm = (w >> 1) * 64, wn = (w & 1) * 64;

    const ushort_t* ag = A + (size_t)(m0 + w * 32 + (ln >> 3)) * K + (ln & 7) * 8;
    const ushort_t* bg = Bt + (size_t)(n0 + w * 32 + (ln >> 3)) * K + (ln & 7) * 8;

    f32x4 acc[4][4] = {};

    for (int k0 = 0; k0 < K; k0 += 64) {
#pragma unroll
        for (int i = 0; i < 4; i++) {
            __builtin_amdgcn_global_load_lds(
                (gptr_t)(const void*)(ag + (size_t)i * 8 * K + k0),
                (lptr_t)(void*)(&sA[(w * 32 + i * 8) * 64]), 16, 0, 0);
            __builtin_amdgcn_global_load_lds(
                (gptr_t)(const void*)(bg + (size_t)i * 8 * K + k0),
                (lptr_t)(void*)(&sB[(w * 32 + i * 8) * 64]), 16, 0, 0);
        }
        __syncthreads();
#pragma unroll
        for (int ks = 0; ks < 2; ks++) {
            bf16x8 af[4], bfr[4];
#pragma unroll
            for (int m = 0; m < 4; m++)
                af[m] = *reinterpret_cast<const bf16x8*>(
                    &sA[(wm + m * 16 + (ln & 15)) * 64 + ks * 32 + (ln >> 4) * 8]);
#pragma unroll
            for (int n = 0; n < 4; n++)
                bfr[n] = *reinterpret_cast<const bf16x8*>(
                    &sB[(wn + n * 16 + (ln & 15)) * 64 + ks * 32 + (ln >> 4) * 8]);
#pragma unroll
            for (int m = 0; m < 4; m++)
#pragma unroll
                for (int n = 0; n < 4; n++)
                    acc[m][n] = __builtin_amdgcn_mfma_f32_16x16x32_bf16(af[m], bfr[n], acc[m][n], 0, 0, 0);
        }
        __syncthreads();
    }

    int cc = ln & 15, qq = ln >> 4;
#pragma unroll
    for (int m = 0; m < 4; m++) {
#pragma unroll
        for (int rr = 0; rr < 4; rr++) {
            int row = m0 + wm + m * 16 + qq * 4 + rr;
#pragma unroll
            for (int n = 0; n < 4; n++)
                C[(size_t)row * Nout + n0 + wn + n * 16 + cc] = f2bf(acc[m][n][rr]);
        }
    }

    float as_[4], ad_[4];
#pragma unroll
    for (int n = 0; n < 4; n++) {
        int col = n0 + wn + n * 16 + cc;
        as_[n] = att_s[col];
        ad_[n] = att_d[col];
    }

    if constexpr (AMODE == 1) {
        int hbase = (n0 + wn) >> 5;
#pragma unroll
        for (int m = 0; m < 4; m++) {
#pragma unroll
            for (int rr = 0; rr < 4; rr++) {
                int row = m0 + wm + m * 16 + qq * 4 + rr;
                float ps0 = acc[m][0][rr] * as_[0] + acc[m][1][rr] * as_[1];
                float ps1 = acc[m][2][rr] * as_[2] + acc[m][3][rr] * as_[3];
                float pd0 = acc[m][0][rr] * ad_[0] + acc[m][1][rr] * ad_[1];
                float pd1 = acc[m][2][rr] * ad_[2] + acc[m][3][rr] * ad_[3];
#pragma unroll
                for (int o = 1; o < 16; o <<= 1) {
                    ps0 += __shfl_xor(ps0, o, 64);
                    ps1 += __shfl_xor(ps1, o, 64);
                    pd0 += __shfl_xor(pd0, o, 64);
                    pd1 += __shfl_xor(pd1, o, 64);
                }
                if (cc == 0 && row < N) {
                    als[row * NHEAD + hbase] = ps0;
                    als[row * NHEAD + hbase + 1] = ps1;
                    ald[row * NHEAD + hbase] = pd0;
                    ald[row * NHEAD + hbase + 1] = pd1;
                }
            }
        }
    } else {
        __shared__ float sh_s[2][128];
        __shared__ float sh_d[2][128];
#pragma unroll
        for (int m = 0; m < 4; m++) {
#pragma unroll
            for (int rr = 0; rr < 4; rr++) {
                int rib = wm + m * 16 + qq * 4 + rr;
                float ps = acc[m][0][rr] * as_[0] + acc[m][1][rr] * as_[1] +
                           acc[m][2][rr] * as_[2] + acc[m][3][rr] * as_[3];
                float pd = acc[m][0][rr] * ad_[0] + acc[m][1][rr] * ad_[1] +
                           acc[m][2][rr] * ad_[2] + acc[m][3][rr] * ad_[3];
#pragma unroll
                for (int o = 1; o < 16; o <<= 1) {
                    ps += __shfl_xor(ps, o, 64);
                    pd += __shfl_xor(pd, o, 64);
                }
                if (cc == 0) {
                    sh_s[wn >> 6][rib] = ps;
                    sh_d[wn >> 6][rib] = pd;
                }
            }
        }
        __syncthreads();
        if (t < 128) {
            int row = m0 + t;
            if (row < N) {
                als[row] = sh_s[0][t] + sh_s[1][t];
                ald[row] = sh_d[0][t] + sh_d[1][t];
            }
        }
    }
}

// -------- layer-1 aggregation: 1 WAVE per node, no-max softmax, selfa fused in-loop --------
// staging role: lane l = e8*8+h  (edge-slot e8 = l>>3, head h = l&7)
// gather  role: lane l covers channels 4l..4l+3, head hd = l>>3
__global__ void __launch_bounds__(64) node_agg1(
    const ushort_t* __restrict__ h1b, const float* __restrict__ als, const float* __restrict__ ald,
    const float* __restrict__ rel_alpha, const int* __restrict__ rowptr,
    const int* __restrict__ src_pk,
    const float* __restrict__ b1, const float* __restrict__ g1, const float* __restrict__ beta1,
    ushort_t* __restrict__ out, int N) {
    __shared__ float sh_rel[NREL * NHEAD];
    __shared__ float sh_w[64 * NHEAD];
    __shared__ unsigned sh_off[64];
    int l = threadIdx.x;
    int i = blockIdx.x;
    if (i >= N) return;
    if (l < NREL * NHEAD) sh_rel[l] = rel_alpha[l];
    int h = l & 7;     // staging head
    int e8 = l >> 3;   // staging edge-slot; also gather head hd
    float als_i = als[i * NHEAD + h];
    float ald_h = ald[i * NHEAD + h];
    float c0, c1, c2, c3;
    {
        u16x4 v = *reinterpret_cast<const u16x4*>(h1b + (size_t)i * HID + 4 * l);
        c0 = b2f(v[0]); c1 = b2f(v[1]); c2 = b2f(v[2]); c3 = b2f(v[3]);
    }
    int base = rowptr[i];
    int deg = rowptr[i + 1] - base;
    const char* hb = reinterpret_cast<const char*>(h1b);
    float acc0 = 0.f, acc1 = 0.f, acc2 = 0.f, acc3 = 0.f;
    float csum = 0.f, rs = 0.f;
    __syncthreads();  // publish sh_rel (single-wave barrier, cheap)
    for (int cs = 0; cs < deg; cs += 64) {
        int c = min(64, deg - cs);
        for (int p = 0; p * 8 < c; p++) {
            int e = p * 8 + e8;
            if (e < c) {
                int pk = src_pk[base + cs + e];
                int sv = pk & 0xFFFFFF;
                int tv = (unsigned)pk >> 24;
                float ra = sh_rel[tv * NHEAD + h];
                float a = als[sv * NHEAD + h] + ald_h + ra;
                float w = __expf(fminf(leaky(a), 40.f));
                sh_w[e * NHEAD + h] = w;
                csum += w;
                rs += ra;
                if (h == 0) sh_off[e] = (unsigned)sv * (HID * 2);
            }
        }
        __syncthreads();
        int e = 0;
        for (; e + 8 <= c; e += 8) {
            unsigned ofs[8];
            float wt[8];
            u16x4 v[8];
#pragma unroll
            for (int jj = 0; jj < 8; jj++) {
                ofs[jj] = sh_off[e + jj];
                wt[jj] = sh_w[(e + jj) * NHEAD + e8];
            }
#pragma unroll
            for (int jj = 0; jj < 8; jj++)
                v[jj] = *reinterpret_cast<const u16x4*>(hb + ofs[jj] + 8 * l);
#pragma unroll
            for (int jj = 0; jj < 8; jj++) {
                acc0 += wt[jj] * b2f(v[jj][0]);
                acc1 += wt[jj] * b2f(v[jj][1]);
                acc2 += wt[jj] * b2f(v[jj][2]);
                acc3 += wt[jj] * b2f(v[jj][3]);
            }
        }
        for (; e < c; e++) {
            unsigned o0 = sh_off[e];
            float w0 = sh_w[e * NHEAD + e8];
            u16x4 v0 = *reinterpret_cast<const u16x4*>(hb + o0 + 8 * l);
            acc0 += w0 * b2f(v0[0]); acc1 += w0 * b2f(v0[1]);
            acc2 += w0 * b2f(v0[2]); acc3 += w0 * b2f(v0[3]);
        }
        __syncthreads();  // before next chunk overwrites sh_w/sh_off
    }
    // per-head totals: reduce over edge-slot lanes (strides 8,16,32)
    for (int o = 8; o < 64; o <<= 1) {
        csum += __shfl_xor(csum, o, 64);
        rs += __shfl_xor(rs, o, 64);
    }
    float selfa = rs / fmaxf((float)deg, 1.0f);
    float wself = __expf(fminf(leaky(als_i + ald_h + selfa), 40.f));
    float stot = csum + wself;
    // gather role needs head hd = e8's values: held by lane hd (lane<8 has h=lane, e8=0)
    float s_g = __shfl(stot, e8, 64);
    float w_g = __shfl(wself, e8, 64);
    acc0 += w_g * c0; acc1 += w_g * c1; acc2 += w_g * c2; acc3 += w_g * c3;
    float inv = 1.0f / (s_g + 1e-16f);
    float4 bb = *reinterpret_cast<const float4*>(b1 + 4 * l);
    float y0 = acc0 * inv + bb.x, y1 = acc1 * inv + bb.y;
    float y2 = acc2 * inv + bb.z, y3 = acc3 * inv + bb.w;
    float su = y0 + y1 + y2 + y3;
    float sq = y0 * y0 + y1 * y1 + y2 * y2 + y3 * y3;
    for (int o = 1; o < 64; o <<= 1) {
        su += __shfl_xor(su, o, 64);
        sq += __shfl_xor(sq, o, 64);
    }
    float mean = su * (1.f / 256.f);
    float var = sq * (1.f / 256.f) - mean * mean;
    float rstd = rsqrtf(var + 1e-5f);
    float4 gg = *reinterpret_cast<const float4*>(g1 + 4 * l);
    float4 be = *reinterpret_cast<const float4*>(beta1 + 4 * l);
    float z0 = (y0 - mean) * rstd * gg.x + be.x;
    float z1 = (y1 - mean) * rstd * gg.y + be.y;
    float z2 = (y2 - mean) * rstd * gg.z + be.z;
    float z3 = (y3 - mean) * rstd * gg.w + be.w;
    u16x4 ov;
    ov[0] = f2bf(z0 > 0.f ? z0 : __expf(z0) - 1.f);
    ov[1] = f2bf(z1 > 0.f ? z1 : __expf(z1) - 1.f);
    ov[2] = f2bf(z2 > 0.f ? z2 : __expf(z2) - 1.f);
    ov[3] = f2bf(z3 > 0.f ? z3 : __expf(z3) - 1.f);
    *reinterpret_cast<u16x4*>(out + (size_t)i * HID + 4 * l) = ov;
}

// -------- layer-2 aggregation: 1 WAVE per node, no-max softmax (1 head) --------
__global__ void __launch_bounds__(64) node_agg2(const ushort_t* __restrict__ h2b,
                                                const float* __restrict__ als,
                                                const float* __restrict__ ald,
                                                const int* __restrict__ rowptr,
                                                const int* __restrict__ src_pk,
                                                const float* __restrict__ b2,
                                                const float* __restrict__ g2,
                                                const float* __restrict__ beta2,
                                                float* __restrict__ out, int N) {
    __shared__ float sh_w[64];
    __shared__ unsigned sh_off[64];
    int l = threadIdx.x;
    int i = blockIdx.x;
    if (i >= N) return;
    float aldi = ald[i];
    float alsi = als[i];
    float c0, c1;
    {
        u16x2 v = *reinterpret_cast<const u16x2*>(h2b + (size_t)i * OUT_DIM + 2 * l);
        c0 = b2f(v[0]); c1 = b2f(v[1]);
    }
    int base = rowptr[i];
    int deg = rowptr[i + 1] - base;
    const char* hb = reinterpret_cast<const char*>(h2b);
    float acc0 = 0.f, acc1 = 0.f;
    float csum = 0.f;
    for (int cs = 0; cs < deg; cs += 64) {
        int c = min(64, deg - cs);
        float w = 0.f;
        if (l < c) {
            int sv = src_pk[base + cs + l] & 0xFFFFFF;
            w = __expf(fminf(leaky(als[sv] + aldi), 40.f));
            sh_off[l] = (unsigned)sv * (OUT_DIM * 2);
        }
        sh_w[l] = w;
        csum += w;
        __syncthreads();
        int e = 0;
        for (; e + 8 <= c; e += 8) {
            unsigned ofs[8];
            float wt[8];
            u16x2 v[8];
#pragma unroll
            for (int jj = 0; jj < 8; jj++) {
                ofs[jj] = sh_off[e + jj];
                wt[jj] = sh_w[e + jj];
            }
#pragma unroll
            for (int jj = 0; jj < 8; jj++)
                v[jj] = *reinterpret_cast<const u16x2*>(hb + ofs[jj] + 4 * l);
#pragma unroll
            for (int jj = 0; jj < 8; jj++) {
                acc0 += wt[jj] * b2f(v[jj][0]);
                acc1 += wt[jj] * b2f(v[jj][1]);
            }
        }
        for (; e < c; e++) {
            unsigned o0 = sh_off[e];
            float w0 = sh_w[e];
            u16x2 v0 = *reinterpret_cast<const u16x2*>(hb + o0 + 4 * l);
            acc0 += w0 * b2f(v0[0]); acc1 += w0 * b2f(v0[1]);
        }
        __syncthreads();
    }
    for (int o = 1; o < 64; o <<= 1) csum += __shfl_xor(csum, o, 64);
    float wself = __expf(fminf(leaky(alsi + aldi), 40.f));
    float s = csum + wself;
    acc0 += wself * c0; acc1 += wself * c1;
    float inv = 1.0f / (s + 1e-16f);
    float2 bb = *reinterpret_cast<const float2*>(b2 + 2 * l);
    float y0 = acc0 * inv + bb.x, y1 = acc1 * inv + bb.y;
    float su = y0 + y1, sq = y0 * y0 + y1 * y1;
    for (int o = 1; o < 64; o <<= 1) {
        su += __shfl_xor(su, o, 64);
        sq += __shfl_xor(sq, o, 64);
    }
    float mean = su * (1.f / 128.f);
    float var = sq * (1.f / 128.f) - mean * mean;
    float rstd = rsqrtf(var + 1e-5f);
    float2 gg = *reinterpret_cast<const float2*>(g2 + 2 * l);
    float2 be = *reinterpret_cast<const float2*>(beta2 + 2 * l);
    float2 ov;
    ov.x = (y0 - mean) * rstd * gg.x + be.x;
    ov.y = (y1 - mean) * rstd * gg.y + be.y;
    *reinterpret_cast<float2*>(out + (size_t)i * OUT_DIM + 2 * l) = ov;
}

extern "C" void kernel_launch(void* const* d_in, const int* in_sizes, int n_in,
                              void* d_out, int out_size, void* d_ws, size_t ws_size,
                              hipStream_t stream) {
    const float* x = (const float*)d_in[0];
    const int* ei = (const int*)d_in[1];
    const int* ety = (const int*)d_in[2];
    const float* rel_emb = (const float*)d_in[3];
    const float* W1 = (const float*)d_in[4];
    const float* att_s1 = (const float*)d_in[5];
    const float* att_d1 = (const float*)d_in[6];
    const float* We1 = (const float*)d_in[7];
    const float* att_e1 = (const float*)d_in[8];
    const float* b1 = (const float*)d_in[9];
    const float* g1 = (const float*)d_in[10];
    const float* beta1 = (const float*)d_in[11];
    const float* W2 = (const float*)d_in[12];
    const float* att_s2 = (const float*)d_in[13];
    const float* att_d2 = (const float*)d_in[14];
    const float* b2 = (const float*)d_in[15];
    const float* g2 = (const float*)d_in[16];
    const float* beta2 = (const float*)d_in[17];

    int N = in_sizes[0] / IN_DIM;
    int E = in_sizes[1] / 2;
    int Mpad = ((N + 127) / 128) * 128;
    const int* src0 = ei;
    const int* dst0 = ei + E;

    char* ws = (char*)d_ws;
    size_t off = 0;
    auto alloc = [&](size_t bytes) -> void* {
        off = (off + 255) & ~(size_t)255;
        void* p = ws + off;
        off += bytes;
        return p;
    };
    int* deg = (int*)alloc((size_t)N * 4);
    int* fill = (int*)alloc((size_t)N * 4);
    int* rowptr = (int*)alloc((size_t)(N + 1) * 4);
    int* src_pk = (int*)alloc((size_t)E * 4);
    int nb = (N + 1023) >> 10;
    int* bsum = (int*)alloc((size_t)nb * 4);
    int* bbase = (int*)alloc((size_t)nb * 4);
    float* rel_alpha = (float*)alloc(NREL * NHEAD * 4);
    float* als1 = (float*)alloc((size_t)N * NHEAD * 4);
    float* ald1 = (float*)alloc((size_t)N * NHEAD * 4);
    float* al2s = (float*)alloc((size_t)N * 4);
    float* al2d = (float*)alloc((size_t)N * 4);
    ushort_t* W1t = (ushort_t*)alloc((size_t)HID * IN_DIM * 2);
    ushort_t* W2t = (ushort_t*)alloc((size_t)OUT_DIM * HID * 2);
    ushort_t* h1b = (ushort_t*)alloc((size_t)Mpad * HID * 2);
    ushort_t* xb = (ushort_t*)alloc((size_t)Mpad * IN_DIM * 2);
    ushort_t* h1pb = xb;   // xb dead after gemm1
    ushort_t* h2b = h1b;   // h1b dead after node_agg1

    hipMemsetAsync(deg, 0, (size_t)N * 4, stream);
    hipMemsetAsync(fill, 0, (size_t)N * 4, stream);

    int eb = (E + 255) / 256;
    count_kernel<<<eb, 256, 0, stream>>>(dst0, deg, E);
    scanA<<<nb, 256, 0, stream>>>(deg, bsum, N);
    scanB<<<1, 256, 0, stream>>>(bsum, bbase, rowptr, nb, N);
    scanC<<<nb, 256, 0, stream>>>(deg, bbase, rowptr, N);
    scatter_kernel<<<eb, 256, 0, stream>>>(src0, dst0, ety, rowptr, fill, src_pk, E);
    rel_alpha_kernel<<<1, 64, 0, stream>>>(rel_emb, We1, att_e1, rel_alpha);
    transpose_conv<<<(IN_DIM * HID + 255) / 256, 256, 0, stream>>>(W1, W1t, IN_DIM, HID);
    transpose_conv<<<(HID * OUT_DIM + 255) / 256, 256, 0, stream>>>(W2, W2t, HID, OUT_DIM);
    conv_bf16<<<2048, 256, 0, stream>>>(x, xb, N * IN_DIM, Mpad * IN_DIM);

    int NB1 = HID / 128;
    int T1 = (Mpad / 128) * NB1;
    gemm_lds<1><<<T1, 256, 0, stream>>>(xb, W1t, h1b, IN_DIM, HID, NB1,
                                        att_s1, att_d1, als1, ald1, N);
    hipMemsetAsync(h1pb + (size_t)N * HID, 0, (size_t)(Mpad - N) * HID * 2, stream);
    node_agg1<<<N, 64, 0, stream>>>(h1b, als1, ald1, rel_alpha, rowptr, src_pk,
                                    b1, g1, beta1, h1pb, N);

    int NB2 = OUT_DIM / 128;
    int T2 = (Mpad / 128) * NB2;
    gemm_lds<2><<<T2, 256, 0, stream>>>(h1pb, W2t, h2b, HID, OUT_DIM, NB2,
                                        att_s2, att_d2, al2s, al2d, N);
    node_agg2<<<N, 64, 0, stream>>>(h2b, al2s, al2d, rowptr, src_pk, b2, g2, beta2,
                                    (float*)d_out, N);
}